// Round 4
// baseline (230.224 us; speedup 1.0000x reference)
//
#include <hip/hip_runtime.h>
#include <hip/hip_bf16.h>
#include <cstdint>
#include <cstddef>

#define HW   1024   // H*W tokens
#define NC   512    // channels
#define NB   16     // batch
#define EPSV 1e-5f

typedef __hip_bfloat16 bf16;
typedef __attribute__((ext_vector_type(8))) __bf16 bf16x8;
typedef __attribute__((ext_vector_type(4))) float f32x4;

__device__ __forceinline__ float b2f(bf16 h) { return __bfloat162float(h); }

__device__ __forceinline__ void gload16(const void* g, void* l) {
  __builtin_amdgcn_global_load_lds(
      (const __attribute__((address_space(1))) uint32_t*)g,
      (__attribute__((address_space(3))) uint32_t*)l, 16, 0, 0);
}

// ---------------- weight fp32 -> bf16 convert ----------------
__global__ __launch_bounds__(256) void cvt_w_kernel(
    const float* __restrict__ wi, const float* __restrict__ wo,
    bf16* __restrict__ wib, bf16* __restrict__ wob) {
  int i = blockIdx.x * 256 + threadIdx.x;
  const float4* src;
  bf16* dst;
  int j;
  if (i < 196608) { src = (const float4*)wi; j = i; dst = wib; }
  else            { src = (const float4*)wo; j = i - 196608; dst = wob; }
  float4 v = src[j];
  union { bf16 h[4]; uint2 u; } p;
  p.h[0] = __float2bfloat16(v.x); p.h[1] = __float2bfloat16(v.y);
  p.h[2] = __float2bfloat16(v.z); p.h[3] = __float2bfloat16(v.w);
  *(uint2*)&dst[(size_t)j * 4] = p.u;
}

// ---------------- GroupNorm -> xn token-major bf16 [b][hw][c] ----------------
__global__ __launch_bounds__(256) void gn_kernel(
    const float* __restrict__ x, const float* __restrict__ gamma,
    const float* __restrict__ beta, bf16* __restrict__ xn) {
  int blk = blockIdx.x;
  int b = blk >> 5, g = blk & 31;
  size_t base = ((size_t)(b * NC + g * 16)) * HW;
  const float4* src4 = (const float4*)(x + base);
  int t = threadIdx.x;
  float s = 0.f, ss = 0.f;
  float4 v[16];
#pragma unroll
  for (int i = 0; i < 16; ++i) {
    v[i] = src4[t + i * 256];
    s  += v[i].x + v[i].y + v[i].z + v[i].w;
    ss += v[i].x * v[i].x + v[i].y * v[i].y + v[i].z * v[i].z + v[i].w * v[i].w;
  }
  __shared__ float red[256];
  red[t] = s; __syncthreads();
  for (int o = 128; o > 0; o >>= 1) { if (t < o) red[t] += red[t + o]; __syncthreads(); }
  float mean = red[0] * (1.f / 16384.f);
  __syncthreads();
  red[t] = ss; __syncthreads();
  for (int o = 128; o > 0; o >>= 1) { if (t < o) red[t] += red[t + o]; __syncthreads(); }
  float var = red[0] * (1.f / 16384.f) - mean * mean;
  float rstd = rsqrtf(var + EPSV);

  __shared__ bf16 sm[16][1032];
#pragma unroll
  for (int i = 0; i < 16; ++i) {
    int idx = t + i * 256;
    int c = idx >> 8;
    int hw4 = (idx & 255) * 4;
    float gm = gamma[g * 16 + c], bt = beta[g * 16 + c];
    union { bf16 h[4]; uint2 u; } p;
    p.h[0] = __float2bfloat16((v[i].x - mean) * rstd * gm + bt);
    p.h[1] = __float2bfloat16((v[i].y - mean) * rstd * gm + bt);
    p.h[2] = __float2bfloat16((v[i].z - mean) * rstd * gm + bt);
    p.h[3] = __float2bfloat16((v[i].w - mean) * rstd * gm + bt);
    *(uint2*)&sm[c][hw4] = p.u;
  }
  __syncthreads();
  bf16* dst = xn + (size_t)b * HW * NC + g * 16;
#pragma unroll
  for (int it = 0; it < 8; ++it) {
    int u = it * 256 + t;
    int hw = u >> 1;
    int c8 = (u & 1) * 8;
    union { bf16 h[8]; uint4 q; } p;
#pragma unroll
    for (int j = 0; j < 8; ++j) p.h[j] = sm[c8 + j][hw];
    *(uint4*)&dst[(size_t)hw * NC + c8] = p.q;
  }
}

// ---------------- universal MFMA GEMM: C[M][N] = A[M][K] * B^T[N][K] --------
// MODE 0: bf16 store transposed  C[col*ldc+row], bias[row]        (qk proj)
// MODE 1: bf16 store row-major   C[row*ldc+col], optional bias    (v proj)
// MODE 3: f32  store row-major, + bias[row] + resid               (out proj)
template <int MODE>
__global__ __launch_bounds__(256) void gemm_bt(
    const bf16* __restrict__ A, int lda, long long sA,
    const bf16* __restrict__ B, int ldb, long long sB,
    void* __restrict__ Cv, int ldc, long long sC,
    int K,
    const float* __restrict__ bias,
    const float* __restrict__ resid, long long sR,
    float scale) {
  __shared__ bf16 sT[2][128][32];
  int z = blockIdx.z;
  const bf16* Ab = A + (size_t)z * sA;
  const bf16* Bb = B + (size_t)z * sB;
  int n0 = blockIdx.x * 128, m0 = blockIdx.y * 128;
  int t = threadIdx.x;
  int l = t & 63, w = t >> 6;
  int wm = w >> 1, wn = w & 1;

  int srow = t >> 2;
  int scol = (t & 3) * 8;

  f32x4 acc[4][4] = {};

  const bf16* ga0 = Ab + (size_t)(m0 + srow) * lda + scol;
  const bf16* gb0 = Bb + (size_t)(n0 + srow) * ldb + scol;

  for (int k0 = 0; k0 < K; k0 += 32) {
    gload16(ga0 + k0, &sT[0][srow][scol]);
    gload16(ga0 + (size_t)64 * lda + k0, &sT[0][64 + srow][scol]);
    gload16(gb0 + k0, &sT[1][srow][scol]);
    gload16(gb0 + (size_t)64 * ldb + k0, &sT[1][64 + srow][scol]);
    __syncthreads();
    bf16x8 af[4], bfr[4];
    int kc = (l >> 4) * 8;
    int ra = wm * 64 + (l & 15);
    int rb = wn * 64 + (l & 15);
#pragma unroll
    for (int i = 0; i < 4; ++i) {
      af[i]  = *(const bf16x8*)&sT[0][ra + i * 16][kc];
      bfr[i] = *(const bf16x8*)&sT[1][rb + i * 16][kc];
    }
#pragma unroll
    for (int i = 0; i < 4; ++i)
#pragma unroll
      for (int j = 0; j < 4; ++j)
        acc[i][j] = __builtin_amdgcn_mfma_f32_16x16x32_bf16(af[i], bfr[j], acc[i][j], 0, 0, 0);
    __syncthreads();
  }

  int rbase = (l >> 4) * 4;
#pragma unroll
  for (int i = 0; i < 4; ++i) {
    int row = m0 + wm * 64 + i * 16 + rbase;
    float4 bv = make_float4(0.f, 0.f, 0.f, 0.f);
    if (MODE == 0 || MODE == 3) bv = *(const float4*)&bias[row];
    else if (MODE == 1) { if (bias) bv = *(const float4*)&bias[row]; }
#pragma unroll
    for (int j = 0; j < 4; ++j) {
      int col = n0 + wn * 64 + j * 16 + (l & 15);
      if (MODE == 0) {
        bf16* C = (bf16*)Cv + (size_t)z * sC;
        union { bf16 h[4]; uint2 u; } p;
        p.h[0] = __float2bfloat16(acc[i][j][0] + bv.x);
        p.h[1] = __float2bfloat16(acc[i][j][1] + bv.y);
        p.h[2] = __float2bfloat16(acc[i][j][2] + bv.z);
        p.h[3] = __float2bfloat16(acc[i][j][3] + bv.w);
        *(uint2*)&C[(size_t)col * ldc + row] = p.u;
      } else if (MODE == 1) {
        bf16* C = (bf16*)Cv + (size_t)z * sC;
        float bb[4] = {bv.x, bv.y, bv.z, bv.w};
#pragma unroll
        for (int r = 0; r < 4; ++r)
          C[(size_t)(row + r) * ldc + col] = __float2bfloat16(acc[i][j][r] + bb[r]);
      } else {
        float* C = (float*)Cv + (size_t)z * sC;
        float bb[4] = {bv.x, bv.y, bv.z, bv.w};
#pragma unroll
        for (int r = 0; r < 4; ++r) {
          size_t off = (size_t)(row + r) * ldc + col;
          C[off] = acc[i][j][r] + bb[r] + resid[(size_t)z * sR + off];
        }
      }
    }
  }
}

// ---------------- fused flash attention (QBLK=32, 2 blocks/CU) ----------------
// grid: 512 wg = (8 xcd) x (32 qtile) x (2 batch-half), 512 threads (8 waves).
// Q-tile 32 rows in swizzled LDS; K,V gathered from global (L2-resident);
// S^T via mfma(K,Q); online softmax; P in swizzled LDS; O^T via mfma(V,P).
__global__ __launch_bounds__(512, 2) void flash_kernel(
    const bf16* __restrict__ qk, const bf16* __restrict__ vcm,
    bf16* __restrict__ ao) {
  __shared__ bf16 Qs[32 * 512];       // 32KB, swizzled: byte (i*1024+ch*2)^((i&7)<<4)
  __shared__ bf16 Ps[32 * 128];       // 8KB,  swizzled: byte (i*256+j*2)^((i&7)<<4)
  __shared__ float redm[8][32];
  __shared__ float redl[8][32];
  __shared__ float lg[32];

  int id = blockIdx.x;
  int xcd = id & 7, rest = id >> 3;
  int q = rest & 31, bh = rest >> 5;
  int b = xcd + bh * 8;               // batch -> fixed XCD (K/V L2 locality)
  int i0 = q * 32;

  const bf16* qkb = qk + (size_t)b * (HW * 1024);
  const bf16* vb  = vcm + (size_t)b * (NC * HW);
  bf16* aob = ao + (size_t)b * (HW * NC) + (size_t)i0 * NC;

  int t = threadIdx.x;
  int l = t & 63, w = t >> 6;
  int l15 = l & 15, lq = l >> 4;

  // stage Q (rows i0..i0+31, q-half cols 0..511) with pre-swizzled source
  {
    const char* qrow_base = (const char*)qkb + (size_t)i0 * 2048;
#pragma unroll
    for (int it = 0; it < 4; ++it) {
      int s = it * 8192 + t * 16;
      int i = s >> 10;
      int wb = s & 1023;
      const char* src = qrow_base + (size_t)i * 2048 + (wb ^ ((i & 7) << 4));
      gload16(src, ((char*)Qs) + s);
    }
  }
  if (w == 0 && l < 32) lg[l] = 0.f;
  float m_prev[2] = {-1e30f, -1e30f};
  f32x4 o[4][2] = {};                  // [mi: ch frag][ni: i frag]
  const float scl = 0.044194173824159216f;   // 1/sqrt(512)

  __syncthreads();   // B0: Q staged (barrier drains vmcnt), lg init

  for (int tile = 0; tile < 8; ++tile) {
    int jb = tile * 128 + w * 16;      // this wave's 16 K-rows
    // ---- QK^T: S^T[16 j][32 i], K gathered, Q from LDS
    f32x4 s[2] = {};
    const bf16* kp = qkb + (size_t)(jb + l15) * 1024 + 512 + lq * 8;
#pragma unroll
    for (int ks = 0; ks < 16; ++ks) {
      bf16x8 kf = *(const bf16x8*)(kp + ks * 32);
#pragma unroll
      for (int ni = 0; ni < 2; ++ni) {
        int i = ni * 16 + l15;
        int off = (i * 1024 + ks * 64 + lq * 16) ^ ((i & 7) << 4);
        bf16x8 qf = *(const bf16x8*)(((const char*)Qs) + off);
        s[ni] = __builtin_amdgcn_mfma_f32_16x16x32_bf16(kf, qf, s[ni], 0, 0, 0);
      }
    }
    // ---- per-row tile max (scaled domain)
    float tm[2];
#pragma unroll
    for (int ni = 0; ni < 2; ++ni) {
      float v = fmaxf(fmaxf(s[ni][0], s[ni][1]), fmaxf(s[ni][2], s[ni][3]));
      v = fmaxf(v, __shfl_xor(v, 16));
      v = fmaxf(v, __shfl_xor(v, 32));
      tm[ni] = v * scl;
    }
    if (l < 16) {
#pragma unroll
      for (int ni = 0; ni < 2; ++ni) redm[w][ni * 16 + l] = tm[ni];
    }
    __syncthreads();  // B1: redm ready; prev-tile Ps reads done
    float mnew[2], sc[2], psum[2];
#pragma unroll
    for (int ni = 0; ni < 2; ++ni) {
      int row = ni * 16 + l15;
      float v = redm[0][row];
#pragma unroll
      for (int w2 = 1; w2 < 8; ++w2) v = fmaxf(v, redm[w2][row]);
      mnew[ni] = fmaxf(m_prev[ni], v);
      sc[ni] = __expf(m_prev[ni] - mnew[ni]);
      float p0 = __expf(s[ni][0] * scl - mnew[ni]);
      float p1 = __expf(s[ni][1] * scl - mnew[ni]);
      float p2 = __expf(s[ni][2] * scl - mnew[ni]);
      float p3 = __expf(s[ni][3] * scl - mnew[ni]);
      psum[ni] = p0 + p1 + p2 + p3;
      union { bf16 h[4]; uint64_t u; } pk;
      pk.h[0] = __float2bfloat16(p0); pk.h[1] = __float2bfloat16(p1);
      pk.h[2] = __float2bfloat16(p2); pk.h[3] = __float2bfloat16(p3);
      int jl = w * 16 + lq * 4;
      int off = (row * 256 + jl * 2) ^ ((row & 7) << 4);
      *(uint64_t*)(((char*)Ps) + off) = pk.u;
      m_prev[ni] = mnew[ni];
    }
#pragma unroll
    for (int ni = 0; ni < 2; ++ni) {
      float v = psum[ni];
      v += __shfl_xor(v, 16);
      v += __shfl_xor(v, 32);
      psum[ni] = v;
    }
    if (l < 16) {
#pragma unroll
      for (int ni = 0; ni < 2; ++ni) redl[w][ni * 16 + l] = psum[ni];
    }
    __syncthreads();  // B2: redl + Ps ready
    if (w == 0 && l < 16) {
#pragma unroll
      for (int ni = 0; ni < 2; ++ni) {
        int row = ni * 16 + l;
        float v = redl[0][row];
#pragma unroll
        for (int w2 = 1; w2 < 8; ++w2) v += redl[w2][row];
        lg[row] = lg[row] * sc[ni] + v;
      }
    }
    // rescale O (factor depends on i-frag ni only -> lane-local)
#pragma unroll
    for (int mi = 0; mi < 4; ++mi)
#pragma unroll
      for (int ni = 0; ni < 2; ++ni) {
        o[mi][ni][0] *= sc[ni]; o[mi][ni][1] *= sc[ni];
        o[mi][ni][2] *= sc[ni]; o[mi][ni][3] *= sc[ni];
      }
    // ---- PV: O^T[64 ch slice][32 i] += V^T x P
    int chb = w * 64;
#pragma unroll
    for (int ks = 0; ks < 4; ++ks) {
      int j0 = tile * 128 + ks * 32;
      bf16x8 vf[4];
#pragma unroll
      for (int mi = 0; mi < 4; ++mi)
        vf[mi] = *(const bf16x8*)(vb + (size_t)(chb + mi * 16 + l15) * 1024 + j0 + lq * 8);
#pragma unroll
      for (int ni = 0; ni < 2; ++ni) {
        int i = ni * 16 + l15;
        int off = (i * 256 + (ks * 32 + lq * 8) * 2) ^ ((i & 7) << 4);
        bf16x8 pf = *(const bf16x8*)(((const char*)Ps) + off);
#pragma unroll
        for (int mi = 0; mi < 4; ++mi)
          o[mi][ni] = __builtin_amdgcn_mfma_f32_16x16x32_bf16(vf[mi], pf, o[mi][ni], 0, 0, 0);
      }
    }
  }
  __syncthreads();  // B3: lg final
  float linv[2];
#pragma unroll
  for (int ni = 0; ni < 2; ++ni) linv[ni] = 1.f / lg[ni * 16 + l15];
  int chb = w * 64;
#pragma unroll
  for (int mi = 0; mi < 4; ++mi)
#pragma unroll
    for (int ni = 0; ni < 2; ++ni) {
      union { bf16 h[4]; uint64_t u; } pk;
#pragma unroll
      for (int r = 0; r < 4; ++r)
        pk.h[r] = __float2bfloat16(o[mi][ni][r] * linv[ni]);
      int i = ni * 16 + l15;
      int ch = chb + mi * 16 + lq * 4;
      *(uint64_t*)(aob + (size_t)i * NC + ch) = pk.u;
    }
}

extern "C" void kernel_launch(void* const* d_in, const int* in_sizes, int n_in,
                              void* d_out, int out_size, void* d_ws, size_t ws_size,
                              hipStream_t stream) {
  const float* x     = (const float*)d_in[0];
  const float* gamma = (const float*)d_in[1];
  const float* beta  = (const float*)d_in[2];
  const float* w_in  = (const float*)d_in[3];
  const float* b_in  = (const float*)d_in[4];
  const float* w_out = (const float*)d_in[5];
  const float* b_out = (const float*)d_in[6];
  float* out = (float*)d_out;

  char* w = (char*)d_ws;
  bf16* xn  = (bf16*)w;                              // 16 MB, token-major [b][hw][c]
  bf16* ao  = xn;                                    // reuse after projections
  bf16* qk  = (bf16*)(w + ((size_t)16 << 20));       // 32 MB, [b][token][1024] (q|k)
  bf16* vcm = (bf16*)(w + ((size_t)48 << 20));       // 16 MB, [b][c][token]
  bf16* wib = (bf16*)(w + ((size_t)64 << 20));       // 1.5 MB
  bf16* wob = (bf16*)(w + ((size_t)64 << 20) + ((size_t)3 << 19));  // 0.5 MB

  cvt_w_kernel<<<1024, 256, 0, stream>>>(w_in, w_out, wib, wob);
  gn_kernel<<<NB * 32, 256, 0, stream>>>(x, gamma, beta, xn);

  // QK proj: M=1024 (o: q|k), N=1024 (token), K=512 -> qk[b][token][o]
  gemm_bt<0><<<dim3(8, 8, NB), 256, 0, stream>>>(
      wib, 512, 0, xn, 512, 512 * 1024, qk, 1024, 1024 * 1024, 512,
      b_in, nullptr, 0, 0.f);
  // V proj: M=512 (c), N=1024 (token), K=512 -> vcm[b][c][token]
  gemm_bt<1><<<dim3(8, 4, NB), 256, 0, stream>>>(
      wib + 1024 * 512, 512, 0, xn, 512, 512 * 1024, vcm, 1024, 512 * 1024, 512,
      b_in + 1024, nullptr, 0, 0.f);

  // fused attention: scores + softmax + PV
  flash_kernel<<<512, 512, 0, stream>>>(qk, vcm, ao);

  // out proj: M=512 (c), N=1024 (i), K=512 -> out[b][c][i] + bias + residual
  gemm_bt<3><<<dim3(8, 4, NB), 256, 0, stream>>>(
      wob, 512, 0, ao, 512, 524288, out, 1024, 524288, 512,
      b_out, x, 524288, 0.f);
}

// Round 5
// 177.864 us; speedup vs baseline: 1.2944x; 1.2944x over previous
//
#include <hip/hip_runtime.h>
#include <hip/hip_bf16.h>
#include <cstdint>
#include <cstddef>

#define HW   1024   // H*W tokens
#define NC   512    // channels
#define NB   16     // batch
#define EPSV 1e-5f

typedef __hip_bfloat16 bf16;
typedef __attribute__((ext_vector_type(8))) __bf16 bf16x8;
typedef __attribute__((ext_vector_type(4))) float f32x4;

__device__ __forceinline__ float b2f(bf16 h) { return __bfloat162float(h); }

__device__ __forceinline__ void gload16(const void* g, void* l) {
  __builtin_amdgcn_global_load_lds(
      (const __attribute__((address_space(1))) uint32_t*)g,
      (__attribute__((address_space(3))) uint32_t*)l, 16, 0, 0);
}

// ---------------- weight fp32 -> bf16 convert ----------------
__global__ __launch_bounds__(256) void cvt_w_kernel(
    const float* __restrict__ wi, const float* __restrict__ wo,
    bf16* __restrict__ wib, bf16* __restrict__ wob) {
  int i = blockIdx.x * 256 + threadIdx.x;
  const float4* src;
  bf16* dst;
  int j;
  if (i < 196608) { src = (const float4*)wi; j = i; dst = wib; }
  else            { src = (const float4*)wo; j = i - 196608; dst = wob; }
  float4 v = src[j];
  union { bf16 h[4]; uint2 u; } p;
  p.h[0] = __float2bfloat16(v.x); p.h[1] = __float2bfloat16(v.y);
  p.h[2] = __float2bfloat16(v.z); p.h[3] = __float2bfloat16(v.w);
  *(uint2*)&dst[(size_t)j * 4] = p.u;
}

// ---------------- GroupNorm -> xn token-major bf16 [b][hw][c] ----------------
__global__ __launch_bounds__(256) void gn_kernel(
    const float* __restrict__ x, const float* __restrict__ gamma,
    const float* __restrict__ beta, bf16* __restrict__ xn) {
  int blk = blockIdx.x;
  int b = blk >> 5, g = blk & 31;
  size_t base = ((size_t)(b * NC + g * 16)) * HW;
  const float4* src4 = (const float4*)(x + base);
  int t = threadIdx.x;
  float s = 0.f, ss = 0.f;
  float4 v[16];
#pragma unroll
  for (int i = 0; i < 16; ++i) {
    v[i] = src4[t + i * 256];
    s  += v[i].x + v[i].y + v[i].z + v[i].w;
    ss += v[i].x * v[i].x + v[i].y * v[i].y + v[i].z * v[i].z + v[i].w * v[i].w;
  }
  __shared__ float red[256];
  red[t] = s; __syncthreads();
  for (int o = 128; o > 0; o >>= 1) { if (t < o) red[t] += red[t + o]; __syncthreads(); }
  float mean = red[0] * (1.f / 16384.f);
  __syncthreads();
  red[t] = ss; __syncthreads();
  for (int o = 128; o > 0; o >>= 1) { if (t < o) red[t] += red[t + o]; __syncthreads(); }
  float var = red[0] * (1.f / 16384.f) - mean * mean;
  float rstd = rsqrtf(var + EPSV);

  __shared__ bf16 sm[16][1032];
#pragma unroll
  for (int i = 0; i < 16; ++i) {
    int idx = t + i * 256;
    int c = idx >> 8;
    int hw4 = (idx & 255) * 4;
    float gm = gamma[g * 16 + c], bt = beta[g * 16 + c];
    union { bf16 h[4]; uint2 u; } p;
    p.h[0] = __float2bfloat16((v[i].x - mean) * rstd * gm + bt);
    p.h[1] = __float2bfloat16((v[i].y - mean) * rstd * gm + bt);
    p.h[2] = __float2bfloat16((v[i].z - mean) * rstd * gm + bt);
    p.h[3] = __float2bfloat16((v[i].w - mean) * rstd * gm + bt);
    *(uint2*)&sm[c][hw4] = p.u;
  }
  __syncthreads();
  bf16* dst = xn + (size_t)b * HW * NC + g * 16;
#pragma unroll
  for (int it = 0; it < 8; ++it) {
    int u = it * 256 + t;
    int hw = u >> 1;
    int c8 = (u & 1) * 8;
    union { bf16 h[8]; uint4 q; } p;
#pragma unroll
    for (int j = 0; j < 8; ++j) p.h[j] = sm[c8 + j][hw];
    *(uint4*)&dst[(size_t)hw * NC + c8] = p.q;
  }
}

// ---------------- universal MFMA GEMM: C[M][N] = A[M][K] * B^T[N][K] --------
// MODE 0: bf16 store transposed  C[col*ldc+row], bias[row]        (qk proj)
// MODE 1: bf16 store row-major   C[row*ldc+col], optional bias    (v proj)
// MODE 3: f32  store row-major, + bias[row] + resid               (out proj)
template <int MODE>
__global__ __launch_bounds__(256) void gemm_bt(
    const bf16* __restrict__ A, int lda, long long sA,
    const bf16* __restrict__ B, int ldb, long long sB,
    void* __restrict__ Cv, int ldc, long long sC,
    int K,
    const float* __restrict__ bias,
    const float* __restrict__ resid, long long sR,
    float scale) {
  __shared__ bf16 sT[2][128][32];
  int z = blockIdx.z;
  const bf16* Ab = A + (size_t)z * sA;
  const bf16* Bb = B + (size_t)z * sB;
  int n0 = blockIdx.x * 128, m0 = blockIdx.y * 128;
  int t = threadIdx.x;
  int l = t & 63, w = t >> 6;
  int wm = w >> 1, wn = w & 1;

  int srow = t >> 2;
  int scol = (t & 3) * 8;

  f32x4 acc[4][4] = {};

  const bf16* ga0 = Ab + (size_t)(m0 + srow) * lda + scol;
  const bf16* gb0 = Bb + (size_t)(n0 + srow) * ldb + scol;

  for (int k0 = 0; k0 < K; k0 += 32) {
    gload16(ga0 + k0, &sT[0][srow][scol]);
    gload16(ga0 + (size_t)64 * lda + k0, &sT[0][64 + srow][scol]);
    gload16(gb0 + k0, &sT[1][srow][scol]);
    gload16(gb0 + (size_t)64 * ldb + k0, &sT[1][64 + srow][scol]);
    __syncthreads();
    bf16x8 af[4], bfr[4];
    int kc = (l >> 4) * 8;
    int ra = wm * 64 + (l & 15);
    int rb = wn * 64 + (l & 15);
#pragma unroll
    for (int i = 0; i < 4; ++i) {
      af[i]  = *(const bf16x8*)&sT[0][ra + i * 16][kc];
      bfr[i] = *(const bf16x8*)&sT[1][rb + i * 16][kc];
    }
#pragma unroll
    for (int i = 0; i < 4; ++i)
#pragma unroll
      for (int j = 0; j < 4; ++j)
        acc[i][j] = __builtin_amdgcn_mfma_f32_16x16x32_bf16(af[i], bfr[j], acc[i][j], 0, 0, 0);
    __syncthreads();
  }

  int rbase = (l >> 4) * 4;
#pragma unroll
  for (int i = 0; i < 4; ++i) {
    int row = m0 + wm * 64 + i * 16 + rbase;
    float4 bv = make_float4(0.f, 0.f, 0.f, 0.f);
    if (MODE == 0 || MODE == 3) bv = *(const float4*)&bias[row];
    else if (MODE == 1) { if (bias) bv = *(const float4*)&bias[row]; }
#pragma unroll
    for (int j = 0; j < 4; ++j) {
      int col = n0 + wn * 64 + j * 16 + (l & 15);
      if (MODE == 0) {
        bf16* C = (bf16*)Cv + (size_t)z * sC;
        union { bf16 h[4]; uint2 u; } p;
        p.h[0] = __float2bfloat16(acc[i][j][0] + bv.x);
        p.h[1] = __float2bfloat16(acc[i][j][1] + bv.y);
        p.h[2] = __float2bfloat16(acc[i][j][2] + bv.z);
        p.h[3] = __float2bfloat16(acc[i][j][3] + bv.w);
        *(uint2*)&C[(size_t)col * ldc + row] = p.u;
      } else if (MODE == 1) {
        bf16* C = (bf16*)Cv + (size_t)z * sC;
        float bb[4] = {bv.x, bv.y, bv.z, bv.w};
#pragma unroll
        for (int r = 0; r < 4; ++r)
          C[(size_t)(row + r) * ldc + col] = __float2bfloat16(acc[i][j][r] + bb[r]);
      } else {
        float* C = (float*)Cv + (size_t)z * sC;
        float bb[4] = {bv.x, bv.y, bv.z, bv.w};
#pragma unroll
        for (int r = 0; r < 4; ++r) {
          size_t off = (size_t)(row + r) * ldc + col;
          C[off] = acc[i][j][r] + bb[r] + resid[(size_t)z * sR + off];
        }
      }
    }
  }
}

// ---------------- fused flash attention (QBLK=64, reg-pipelined gathers) -----
// grid: 256 wg, 512 threads (8 waves). Q-tile in swizzled LDS; K,V gathered
// from global (L2) with ALL K-frag loads issued up front per tile and V
// double-buffered in registers; S^T=mfma(K,Q); online softmax; O^T=mfma(V,P).
__global__ __launch_bounds__(512, 2) void flash_kernel(
    const bf16* __restrict__ qk, const bf16* __restrict__ vcm,
    bf16* __restrict__ ao) {
  __shared__ bf16 Qs[64 * 512];       // 64KB, swizzled: byte (i*1024+ch*2)^((i&7)<<4)
  __shared__ bf16 Ps[64 * 128];       // 16KB, swizzled: byte (i*256+j*2)^((i&7)<<4)
  __shared__ float redm[8][64];
  __shared__ float redl[8][64];
  __shared__ float lg[64];

  int id = blockIdx.x;
  int xcd = id & 7, rest = id >> 3;
  int q = rest & 15, bh = rest >> 4;
  int b = xcd + bh * 8;               // batch -> fixed XCD (K/V L2 locality)
  int i0 = q * 64;

  const bf16* qkb = qk + (size_t)b * (HW * 1024);
  const bf16* vb  = vcm + (size_t)b * (NC * HW);
  bf16* aob = ao + (size_t)b * (HW * NC) + (size_t)i0 * NC;

  int t = threadIdx.x;
  int l = t & 63, w = t >> 6;
  int l15 = l & 15, lq = l >> 4;

  // stage Q (rows i0..i0+63, q-half cols 0..511) with pre-swizzled source
  {
    const char* qrow_base = (const char*)qkb + (size_t)i0 * 2048;
#pragma unroll
    for (int it = 0; it < 8; ++it) {
      int s = it * 8192 + t * 16;
      int i = s >> 10;
      int wb = s & 1023;
      const char* src = qrow_base + (size_t)i * 2048 + (wb ^ ((i & 7) << 4));
      gload16(src, ((char*)Qs) + s);
    }
  }
  if (w == 0) lg[l] = 0.f;
  float m_prev[4] = {-1e30f, -1e30f, -1e30f, -1e30f};
  f32x4 o[4][4] = {};                  // [mi: ch frag][ni: i frag]
  const float scl = 0.044194173824159216f;   // 1/sqrt(512)
  const int chb = w * 64;
  const bf16* vrow = vb + (size_t)(chb + l15) * 1024 + lq * 8;

  __syncthreads();   // B0: Q staged (barrier drains vmcnt), lg init

  for (int tile = 0; tile < 8; ++tile) {
    int jb = tile * 128 + w * 16;      // this wave's 16 K-rows
    const bf16* kp = qkb + (size_t)(jb + l15) * 1024 + 512 + lq * 8;
    // ---- QK^T: S^T[16 j][64 i]. Issue 8+8 K loads up front (pipelined).
    bf16x8 ka[8], kb2[8];
#pragma unroll
    for (int ks = 0; ks < 8; ++ks) ka[ks] = *(const bf16x8*)(kp + ks * 32);
#pragma unroll
    for (int ks = 0; ks < 8; ++ks) kb2[ks] = *(const bf16x8*)(kp + (8 + ks) * 32);
    f32x4 s[4] = {};
#pragma unroll
    for (int ks = 0; ks < 8; ++ks) {
#pragma unroll
      for (int ni = 0; ni < 4; ++ni) {
        int i = ni * 16 + l15;
        int off = (i * 1024 + ks * 64 + lq * 16) ^ ((i & 7) << 4);
        bf16x8 qf = *(const bf16x8*)(((const char*)Qs) + off);
        s[ni] = __builtin_amdgcn_mfma_f32_16x16x32_bf16(ka[ks], qf, s[ni], 0, 0, 0);
      }
    }
    // issue V batch 0 while second K batch computes (hidden under softmax too)
    bf16x8 va[4], vb2[4];
#pragma unroll
    for (int mi = 0; mi < 4; ++mi)
      va[mi] = *(const bf16x8*)(vrow + (size_t)mi * 16384 + tile * 128);
#pragma unroll
    for (int ks = 0; ks < 8; ++ks) {
#pragma unroll
      for (int ni = 0; ni < 4; ++ni) {
        int i = ni * 16 + l15;
        int off = (i * 1024 + (8 + ks) * 64 + lq * 16) ^ ((i & 7) << 4);
        bf16x8 qf = *(const bf16x8*)(((const char*)Qs) + off);
        s[ni] = __builtin_amdgcn_mfma_f32_16x16x32_bf16(kb2[ks], qf, s[ni], 0, 0, 0);
      }
    }
    // ---- per-row tile max (scaled domain)
    float tm[4];
#pragma unroll
    for (int ni = 0; ni < 4; ++ni) {
      float v = fmaxf(fmaxf(s[ni][0], s[ni][1]), fmaxf(s[ni][2], s[ni][3]));
      v = fmaxf(v, __shfl_xor(v, 16));
      v = fmaxf(v, __shfl_xor(v, 32));
      tm[ni] = v * scl;
    }
    if (l < 16) {
#pragma unroll
      for (int ni = 0; ni < 4; ++ni) redm[w][ni * 16 + l] = tm[ni];
    }
    __syncthreads();  // B1: redm ready; prev-tile Ps reads done
    float mnew[4], sc[4], psum[4];
#pragma unroll
    for (int ni = 0; ni < 4; ++ni) {
      int row = ni * 16 + l15;
      float v = redm[0][row];
#pragma unroll
      for (int w2 = 1; w2 < 8; ++w2) v = fmaxf(v, redm[w2][row]);
      mnew[ni] = fmaxf(m_prev[ni], v);
      sc[ni] = __expf(m_prev[ni] - mnew[ni]);
      float p0 = __expf(s[ni][0] * scl - mnew[ni]);
      float p1 = __expf(s[ni][1] * scl - mnew[ni]);
      float p2 = __expf(s[ni][2] * scl - mnew[ni]);
      float p3 = __expf(s[ni][3] * scl - mnew[ni]);
      psum[ni] = p0 + p1 + p2 + p3;
      union { bf16 h[4]; uint64_t u; } pk;
      pk.h[0] = __float2bfloat16(p0); pk.h[1] = __float2bfloat16(p1);
      pk.h[2] = __float2bfloat16(p2); pk.h[3] = __float2bfloat16(p3);
      int jl = w * 16 + lq * 4;
      int off = (row * 256 + jl * 2) ^ ((row & 7) << 4);
      *(uint64_t*)(((char*)Ps) + off) = pk.u;
      m_prev[ni] = mnew[ni];
    }
#pragma unroll
    for (int ni = 0; ni < 4; ++ni) {
      float v = psum[ni];
      v += __shfl_xor(v, 16);
      v += __shfl_xor(v, 32);
      psum[ni] = v;
    }
    if (l < 16) {
#pragma unroll
      for (int ni = 0; ni < 4; ++ni) redl[w][ni * 16 + l] = psum[ni];
    }
    __syncthreads();  // B2: redl + Ps ready
    if (w == 0 && l < 16) {
#pragma unroll
      for (int ni = 0; ni < 4; ++ni) {
        int row = ni * 16 + l;
        float v = redl[0][row];
#pragma unroll
        for (int w2 = 1; w2 < 8; ++w2) v += redl[w2][row];
        lg[row] = lg[row] * sc[ni] + v;
      }
    }
    // rescale O (factor depends on i-frag ni only -> lane-local)
#pragma unroll
    for (int mi = 0; mi < 4; ++mi)
#pragma unroll
      for (int ni = 0; ni < 4; ++ni) {
        o[mi][ni][0] *= sc[ni]; o[mi][ni][1] *= sc[ni];
        o[mi][ni][2] *= sc[ni]; o[mi][ni][3] *= sc[ni];
      }
    // ---- PV: O^T[64 ch slice][64 i] += V^T x P, V double-buffered in regs
#pragma unroll
    for (int mi = 0; mi < 4; ++mi)                       // issue batch 1
      vb2[mi] = *(const bf16x8*)(vrow + (size_t)mi * 16384 + tile * 128 + 32);
#pragma unroll
    for (int ni = 0; ni < 4; ++ni) {                     // compute batch 0 (va)
      int i = ni * 16 + l15;
      int off = (i * 256 + (lq * 8) * 2) ^ ((i & 7) << 4);
      bf16x8 pf = *(const bf16x8*)(((const char*)Ps) + off);
#pragma unroll
      for (int mi = 0; mi < 4; ++mi)
        o[mi][ni] = __builtin_amdgcn_mfma_f32_16x16x32_bf16(va[mi], pf, o[mi][ni], 0, 0, 0);
    }
#pragma unroll
    for (int mi = 0; mi < 4; ++mi)                       // issue batch 2
      va[mi] = *(const bf16x8*)(vrow + (size_t)mi * 16384 + tile * 128 + 64);
#pragma unroll
    for (int ni = 0; ni < 4; ++ni) {                     // compute batch 1 (vb2)
      int i = ni * 16 + l15;
      int off = (i * 256 + (32 + lq * 8) * 2) ^ ((i & 7) << 4);
      bf16x8 pf = *(const bf16x8*)(((const char*)Ps) + off);
#pragma unroll
      for (int mi = 0; mi < 4; ++mi)
        o[mi][ni] = __builtin_amdgcn_mfma_f32_16x16x32_bf16(vb2[mi], pf, o[mi][ni], 0, 0, 0);
    }
#pragma unroll
    for (int mi = 0; mi < 4; ++mi)                       // issue batch 3
      vb2[mi] = *(const bf16x8*)(vrow + (size_t)mi * 16384 + tile * 128 + 96);
#pragma unroll
    for (int ni = 0; ni < 4; ++ni) {                     // compute batch 2 (va)
      int i = ni * 16 + l15;
      int off = (i * 256 + (64 + lq * 8) * 2) ^ ((i & 7) << 4);
      bf16x8 pf = *(const bf16x8*)(((const char*)Ps) + off);
#pragma unroll
      for (int mi = 0; mi < 4; ++mi)
        o[mi][ni] = __builtin_amdgcn_mfma_f32_16x16x32_bf16(va[mi], pf, o[mi][ni], 0, 0, 0);
    }
#pragma unroll
    for (int ni = 0; ni < 4; ++ni) {                     // compute batch 3 (vb2)
      int i = ni * 16 + l15;
      int off = (i * 256 + (96 + lq * 8) * 2) ^ ((i & 7) << 4);
      bf16x8 pf = *(const bf16x8*)(((const char*)Ps) + off);
#pragma unroll
      for (int mi = 0; mi < 4; ++mi)
        o[mi][ni] = __builtin_amdgcn_mfma_f32_16x16x32_bf16(vb2[mi], pf, o[mi][ni], 0, 0, 0);
    }
  }
  __syncthreads();  // B3: lg final
  float linv[4];
#pragma unroll
  for (int ni = 0; ni < 4; ++ni) linv[ni] = 1.f / lg[ni * 16 + l15];
#pragma unroll
  for (int mi = 0; mi < 4; ++mi)
#pragma unroll
    for (int ni = 0; ni < 4; ++ni) {
      union { bf16 h[4]; uint64_t u; } pk;
#pragma unroll
      for (int r = 0; r < 4; ++r)
        pk.h[r] = __float2bfloat16(o[mi][ni][r] * linv[ni]);
      int i = ni * 16 + l15;
      int ch = chb + mi * 16 + lq * 4;
      *(uint64_t*)(aob + (size_t)i * NC + ch) = pk.u;
    }
}

extern "C" void kernel_launch(void* const* d_in, const int* in_sizes, int n_in,
                              void* d_out, int out_size, void* d_ws, size_t ws_size,
                              hipStream_t stream) {
  const float* x     = (const float*)d_in[0];
  const float* gamma = (const float*)d_in[1];
  const float* beta  = (const float*)d_in[2];
  const float* w_in  = (const float*)d_in[3];
  const float* b_in  = (const float*)d_in[4];
  const float* w_out = (const float*)d_in[5];
  const float* b_out = (const float*)d_in[6];
  float* out = (float*)d_out;

  char* w = (char*)d_ws;
  bf16* xn  = (bf16*)w;                              // 16 MB, token-major [b][hw][c]
  bf16* ao  = xn;                                    // reuse after projections
  bf16* qk  = (bf16*)(w + ((size_t)16 << 20));       // 32 MB, [b][token][1024] (q|k)
  bf16* vcm = (bf16*)(w + ((size_t)48 << 20));       // 16 MB, [b][c][token]
  bf16* wib = (bf16*)(w + ((size_t)64 << 20));       // 1.5 MB
  bf16* wob = (bf16*)(w + ((size_t)64 << 20) + ((size_t)3 << 19));  // 0.5 MB

  cvt_w_kernel<<<1024, 256, 0, stream>>>(w_in, w_out, wib, wob);
  gn_kernel<<<NB * 32, 256, 0, stream>>>(x, gamma, beta, xn);

  // QK proj: M=1024 (o: q|k), N=1024 (token), K=512 -> qk[b][token][o]
  gemm_bt<0><<<dim3(8, 8, NB), 256, 0, stream>>>(
      wib, 512, 0, xn, 512, 512 * 1024, qk, 1024, 1024 * 1024, 512,
      b_in, nullptr, 0, 0.f);
  // V proj: M=512 (c), N=1024 (token), K=512 -> vcm[b][c][token]
  gemm_bt<1><<<dim3(8, 4, NB), 256, 0, stream>>>(
      wib + 1024 * 512, 512, 0, xn, 512, 512 * 1024, vcm, 1024, 512 * 1024, 512,
      b_in + 1024, nullptr, 0, 0.f);

  // fused attention: scores + softmax + PV
  flash_kernel<<<256, 512, 0, stream>>>(qk, vcm, ao);

  // out proj: M=512 (c), N=1024 (i), K=512 -> out[b][c][i] + bias + residual
  gemm_bt<3><<<dim3(8, 4, NB), 256, 0, stream>>>(
      wob, 512, 0, ao, 512, 524288, out, 1024, 524288, 512,
      b_out, x, 524288, 0.f);
}

// Round 6
// 164.198 us; speedup vs baseline: 1.4021x; 1.0832x over previous
//
#include <hip/hip_runtime.h>
#include <hip/hip_bf16.h>
#include <cstdint>
#include <cstddef>

#define HW   1024   // H*W tokens
#define NC   512    // channels
#define NB   16     // batch
#define EPSV 1e-5f

typedef __hip_bfloat16 bf16;
typedef __attribute__((ext_vector_type(8))) __bf16 bf16x8;
typedef __attribute__((ext_vector_type(4))) float f32x4;

__device__ __forceinline__ float b2f(bf16 h) { return __bfloat162float(h); }

__device__ __forceinline__ void gload16(const void* g, void* l) {
  __builtin_amdgcn_global_load_lds(
      (const __attribute__((address_space(1))) uint32_t*)g,
      (__attribute__((address_space(3))) uint32_t*)l, 16, 0, 0);
}

// ---------------- weight fp32 -> bf16 convert ----------------
__global__ __launch_bounds__(256) void cvt_w_kernel(
    const float* __restrict__ wi, const float* __restrict__ wo,
    bf16* __restrict__ wib, bf16* __restrict__ wob) {
  int i = blockIdx.x * 256 + threadIdx.x;
  const float4* src;
  bf16* dst;
  int j;
  if (i < 196608) { src = (const float4*)wi; j = i; dst = wib; }
  else            { src = (const float4*)wo; j = i - 196608; dst = wob; }
  float4 v = src[j];
  union { bf16 h[4]; uint2 u; } p;
  p.h[0] = __float2bfloat16(v.x); p.h[1] = __float2bfloat16(v.y);
  p.h[2] = __float2bfloat16(v.z); p.h[3] = __float2bfloat16(v.w);
  *(uint2*)&dst[(size_t)j * 4] = p.u;
}

// ---------------- GroupNorm -> xn token-major bf16 [b][hw][c] ----------------
__global__ __launch_bounds__(256) void gn_kernel(
    const float* __restrict__ x, const float* __restrict__ gamma,
    const float* __restrict__ beta, bf16* __restrict__ xn) {
  int blk = blockIdx.x;
  int b = blk >> 5, g = blk & 31;
  size_t base = ((size_t)(b * NC + g * 16)) * HW;
  const float4* src4 = (const float4*)(x + base);
  int t = threadIdx.x;
  float s = 0.f, ss = 0.f;
  float4 v[16];
#pragma unroll
  for (int i = 0; i < 16; ++i) {
    v[i] = src4[t + i * 256];
    s  += v[i].x + v[i].y + v[i].z + v[i].w;
    ss += v[i].x * v[i].x + v[i].y * v[i].y + v[i].z * v[i].z + v[i].w * v[i].w;
  }
  __shared__ float red[256];
  red[t] = s; __syncthreads();
  for (int o = 128; o > 0; o >>= 1) { if (t < o) red[t] += red[t + o]; __syncthreads(); }
  float mean = red[0] * (1.f / 16384.f);
  __syncthreads();
  red[t] = ss; __syncthreads();
  for (int o = 128; o > 0; o >>= 1) { if (t < o) red[t] += red[t + o]; __syncthreads(); }
  float var = red[0] * (1.f / 16384.f) - mean * mean;
  float rstd = rsqrtf(var + EPSV);

  __shared__ bf16 sm[16][1032];
#pragma unroll
  for (int i = 0; i < 16; ++i) {
    int idx = t + i * 256;
    int c = idx >> 8;
    int hw4 = (idx & 255) * 4;
    float gm = gamma[g * 16 + c], bt = beta[g * 16 + c];
    union { bf16 h[4]; uint2 u; } p;
    p.h[0] = __float2bfloat16((v[i].x - mean) * rstd * gm + bt);
    p.h[1] = __float2bfloat16((v[i].y - mean) * rstd * gm + bt);
    p.h[2] = __float2bfloat16((v[i].z - mean) * rstd * gm + bt);
    p.h[3] = __float2bfloat16((v[i].w - mean) * rstd * gm + bt);
    *(uint2*)&sm[c][hw4] = p.u;
  }
  __syncthreads();
  bf16* dst = xn + (size_t)b * HW * NC + g * 16;
#pragma unroll
  for (int it = 0; it < 8; ++it) {
    int u = it * 256 + t;
    int hw = u >> 1;
    int c8 = (u & 1) * 8;
    union { bf16 h[8]; uint4 q; } p;
#pragma unroll
    for (int j = 0; j < 8; ++j) p.h[j] = sm[c8 + j][hw];
    *(uint4*)&dst[(size_t)hw * NC + c8] = p.q;
  }
}

// ---------------- universal MFMA GEMM: C[M][N] = A[M][K] * B^T[N][K] --------
// MODE 0: bf16 store transposed  C[col*ldc+row], bias[row]        (qk proj)
// MODE 1: bf16 store row-major   C[row*ldc+col], optional bias    (v proj)
// MODE 3: f32  store row-major, + bias[row] + resid               (out proj)
template <int MODE>
__global__ __launch_bounds__(256) void gemm_bt(
    const bf16* __restrict__ A, int lda, long long sA,
    const bf16* __restrict__ B, int ldb, long long sB,
    void* __restrict__ Cv, int ldc, long long sC,
    int K,
    const float* __restrict__ bias,
    const float* __restrict__ resid, long long sR,
    float scale) {
  __shared__ bf16 sT[2][128][32];
  int z = blockIdx.z;
  const bf16* Ab = A + (size_t)z * sA;
  const bf16* Bb = B + (size_t)z * sB;
  int n0 = blockIdx.x * 128, m0 = blockIdx.y * 128;
  int t = threadIdx.x;
  int l = t & 63, w = t >> 6;
  int wm = w >> 1, wn = w & 1;

  int srow = t >> 2;
  int scol = (t & 3) * 8;

  f32x4 acc[4][4] = {};

  const bf16* ga0 = Ab + (size_t)(m0 + srow) * lda + scol;
  const bf16* gb0 = Bb + (size_t)(n0 + srow) * ldb + scol;

  for (int k0 = 0; k0 < K; k0 += 32) {
    gload16(ga0 + k0, &sT[0][srow][scol]);
    gload16(ga0 + (size_t)64 * lda + k0, &sT[0][64 + srow][scol]);
    gload16(gb0 + k0, &sT[1][srow][scol]);
    gload16(gb0 + (size_t)64 * ldb + k0, &sT[1][64 + srow][scol]);
    __syncthreads();
    bf16x8 af[4], bfr[4];
    int kc = (l >> 4) * 8;
    int ra = wm * 64 + (l & 15);
    int rb = wn * 64 + (l & 15);
#pragma unroll
    for (int i = 0; i < 4; ++i) {
      af[i]  = *(const bf16x8*)&sT[0][ra + i * 16][kc];
      bfr[i] = *(const bf16x8*)&sT[1][rb + i * 16][kc];
    }
#pragma unroll
    for (int i = 0; i < 4; ++i)
#pragma unroll
      for (int j = 0; j < 4; ++j)
        acc[i][j] = __builtin_amdgcn_mfma_f32_16x16x32_bf16(af[i], bfr[j], acc[i][j], 0, 0, 0);
    __syncthreads();
  }

  int rbase = (l >> 4) * 4;
#pragma unroll
  for (int i = 0; i < 4; ++i) {
    int row = m0 + wm * 64 + i * 16 + rbase;
    float4 bv = make_float4(0.f, 0.f, 0.f, 0.f);
    if (MODE == 0 || MODE == 3) bv = *(const float4*)&bias[row];
    else if (MODE == 1) { if (bias) bv = *(const float4*)&bias[row]; }
#pragma unroll
    for (int j = 0; j < 4; ++j) {
      int col = n0 + wn * 64 + j * 16 + (l & 15);
      if (MODE == 0) {
        bf16* C = (bf16*)Cv + (size_t)z * sC;
        union { bf16 h[4]; uint2 u; } p;
        p.h[0] = __float2bfloat16(acc[i][j][0] + bv.x);
        p.h[1] = __float2bfloat16(acc[i][j][1] + bv.y);
        p.h[2] = __float2bfloat16(acc[i][j][2] + bv.z);
        p.h[3] = __float2bfloat16(acc[i][j][3] + bv.w);
        *(uint2*)&C[(size_t)col * ldc + row] = p.u;
      } else if (MODE == 1) {
        bf16* C = (bf16*)Cv + (size_t)z * sC;
        float bb[4] = {bv.x, bv.y, bv.z, bv.w};
#pragma unroll
        for (int r = 0; r < 4; ++r)
          C[(size_t)(row + r) * ldc + col] = __float2bfloat16(acc[i][j][r] + bb[r]);
      } else {
        float* C = (float*)Cv + (size_t)z * sC;
        float bb[4] = {bv.x, bv.y, bv.z, bv.w};
#pragma unroll
        for (int r = 0; r < 4; ++r) {
          size_t off = (size_t)(row + r) * ldc + col;
          C[off] = acc[i][j][r] + bb[r] + resid[(size_t)z * sR + off];
        }
      }
    }
  }
}

// ---------------- fused flash attention (no-max softmax, 1 barrier/tile) ----
// grid: 256 wg, 512 threads (8 waves). Q-tile in swizzled LDS; K,V gathered
// from global (L2). exp(s) computed WITHOUT max subtraction (|s|<~8 for
// normalized inputs; fp32-safe; algebraically identical to softmax). Each
// wave keeps its partial row-sum in registers; one cross-wave combine at end.
// Ps double-buffered -> exactly one __syncthreads per KV tile.
__global__ __launch_bounds__(512, 2) void flash_kernel(
    const bf16* __restrict__ qk, const bf16* __restrict__ vcm,
    bf16* __restrict__ ao) {
  __shared__ bf16 Qs[64 * 512];       // 64KB, swizzled: byte (i*1024+ch*2)^((i&7)<<4)
  __shared__ bf16 Ps[2][64 * 128];    // 2x16KB, swizzled: byte (i*256+j*2)^((i&7)<<4)
  __shared__ float redl[8][64];

  int id = blockIdx.x;
  int xcd = id & 7, rest = id >> 3;
  int q = rest & 15, bh = rest >> 4;
  int b = xcd + bh * 8;               // batch -> fixed XCD (K/V L2 locality)
  int i0 = q * 64;

  const bf16* qkb = qk + (size_t)b * (HW * 1024);
  const bf16* vb  = vcm + (size_t)b * (NC * HW);
  bf16* aob = ao + (size_t)b * (HW * NC) + (size_t)i0 * NC;

  int t = threadIdx.x;
  int l = t & 63, w = t >> 6;
  int l15 = l & 15, lq = l >> 4;

  // stage Q (rows i0..i0+63, q-half cols 0..511) with pre-swizzled source
  {
    const char* qrow_base = (const char*)qkb + (size_t)i0 * 2048;
#pragma unroll
    for (int it = 0; it < 8; ++it) {
      int s = it * 8192 + t * 16;
      int i = s >> 10;
      int wb = s & 1023;
      const char* src = qrow_base + (size_t)i * 2048 + (wb ^ ((i & 7) << 4));
      gload16(src, ((char*)Qs) + s);
    }
  }
  float lacc[4] = {0.f, 0.f, 0.f, 0.f};   // per-lane partial row sums
  f32x4 o[4][4] = {};                      // [mi: ch frag][ni: i frag]
  const float scl = 0.044194173824159216f; // 1/sqrt(512)
  const int chb = w * 64;
  const bf16* vrow = vb + (size_t)(chb + l15) * 1024 + lq * 8;

  __syncthreads();   // B0: Q staged (barrier drains vmcnt)

  for (int tile = 0; tile < 8; ++tile) {
    int cur = tile & 1;
    char* Pcur = ((char*)Ps) + cur * 16384;
    int jb = tile * 128 + w * 16;      // this wave's 16 K-rows
    const bf16* kp = qkb + (size_t)(jb + l15) * 1024 + 512 + lq * 8;
    // ---- QK^T: S^T[16 j][64 i], K gathered, Q from LDS
    f32x4 s[4] = {};
#pragma unroll
    for (int ks = 0; ks < 16; ++ks) {
      bf16x8 kf = *(const bf16x8*)(kp + ks * 32);
#pragma unroll
      for (int ni = 0; ni < 4; ++ni) {
        int i = ni * 16 + l15;
        int off = (i * 1024 + ks * 64 + lq * 16) ^ ((i & 7) << 4);
        bf16x8 qf = *(const bf16x8*)(((const char*)Qs) + off);
        s[ni] = __builtin_amdgcn_mfma_f32_16x16x32_bf16(kf, qf, s[ni], 0, 0, 0);
      }
    }
    // ---- P = exp(s*scl) (no max subtraction), pack to LDS, accumulate sums
#pragma unroll
    for (int ni = 0; ni < 4; ++ni) {
      int row = ni * 16 + l15;
      float p0 = __expf(s[ni][0] * scl);
      float p1 = __expf(s[ni][1] * scl);
      float p2 = __expf(s[ni][2] * scl);
      float p3 = __expf(s[ni][3] * scl);
      lacc[ni] += p0 + p1 + p2 + p3;
      union { bf16 h[4]; uint64_t u; } pk;
      pk.h[0] = __float2bfloat16(p0); pk.h[1] = __float2bfloat16(p1);
      pk.h[2] = __float2bfloat16(p2); pk.h[3] = __float2bfloat16(p3);
      int jl = w * 16 + lq * 4;
      int off = (row * 256 + jl * 2) ^ ((row & 7) << 4);
      *(uint64_t*)(Pcur + off) = pk.u;
    }
    // prefetch first V batch before the barrier (hides L2 latency under it)
    bf16x8 va0[4];
#pragma unroll
    for (int mi = 0; mi < 4; ++mi)
      va0[mi] = *(const bf16x8*)(vrow + (size_t)mi * 16384 + tile * 128);
    __syncthreads();  // B1: Ps[cur] complete (only barrier in the tile loop)
    // ---- PV: O^T[64 ch slice][64 i] += V^T x P
#pragma unroll
    for (int ks = 0; ks < 4; ++ks) {
      bf16x8 vf[4];
#pragma unroll
      for (int mi = 0; mi < 4; ++mi)
        vf[mi] = (ks == 0) ? va0[mi]
               : *(const bf16x8*)(vrow + (size_t)mi * 16384 + tile * 128 + ks * 32);
#pragma unroll
      for (int ni = 0; ni < 4; ++ni) {
        int i = ni * 16 + l15;
        int off = (i * 256 + (ks * 32 + lq * 8) * 2) ^ ((i & 7) << 4);
        bf16x8 pf = *(const bf16x8*)(Pcur + off);
#pragma unroll
        for (int mi = 0; mi < 4; ++mi)
          o[mi][ni] = __builtin_amdgcn_mfma_f32_16x16x32_bf16(vf[mi], pf, o[mi][ni], 0, 0, 0);
      }
    }
  }
  // ---- final row-sum combine: lanes -> wave partial -> cross-wave
#pragma unroll
  for (int ni = 0; ni < 4; ++ni) {
    float v = lacc[ni];
    v += __shfl_xor(v, 16);
    v += __shfl_xor(v, 32);
    if (l < 16) redl[w][ni * 16 + l] = v;
  }
  __syncthreads();  // B2: redl ready (all PV reads of Ps already done)
  float linv[4];
#pragma unroll
  for (int ni = 0; ni < 4; ++ni) {
    int row = ni * 16 + l15;
    float v = redl[0][row];
#pragma unroll
    for (int w2 = 1; w2 < 8; ++w2) v += redl[w2][row];
    linv[ni] = 1.f / v;
  }
#pragma unroll
  for (int mi = 0; mi < 4; ++mi)
#pragma unroll
    for (int ni = 0; ni < 4; ++ni) {
      union { bf16 h[4]; uint64_t u; } pk;
#pragma unroll
      for (int r = 0; r < 4; ++r)
        pk.h[r] = __float2bfloat16(o[mi][ni][r] * linv[ni]);
      int i = ni * 16 + l15;
      int ch = chb + mi * 16 + lq * 4;
      *(uint64_t*)(aob + (size_t)i * NC + ch) = pk.u;
    }
}

extern "C" void kernel_launch(void* const* d_in, const int* in_sizes, int n_in,
                              void* d_out, int out_size, void* d_ws, size_t ws_size,
                              hipStream_t stream) {
  const float* x     = (const float*)d_in[0];
  const float* gamma = (const float*)d_in[1];
  const float* beta  = (const float*)d_in[2];
  const float* w_in  = (const float*)d_in[3];
  const float* b_in  = (const float*)d_in[4];
  const float* w_out = (const float*)d_in[5];
  const float* b_out = (const float*)d_in[6];
  float* out = (float*)d_out;

  char* w = (char*)d_ws;
  bf16* xn  = (bf16*)w;                              // 16 MB, token-major [b][hw][c]
  bf16* ao  = xn;                                    // reuse after projections
  bf16* qk  = (bf16*)(w + ((size_t)16 << 20));       // 32 MB, [b][token][1024] (q|k)
  bf16* vcm = (bf16*)(w + ((size_t)48 << 20));       // 16 MB, [b][c][token]
  bf16* wib = (bf16*)(w + ((size_t)64 << 20));       // 1.5 MB
  bf16* wob = (bf16*)(w + ((size_t)64 << 20) + ((size_t)3 << 19));  // 0.5 MB

  cvt_w_kernel<<<1024, 256, 0, stream>>>(w_in, w_out, wib, wob);
  gn_kernel<<<NB * 32, 256, 0, stream>>>(x, gamma, beta, xn);

  // QK proj: M=1024 (o: q|k), N=1024 (token), K=512 -> qk[b][token][o]
  gemm_bt<0><<<dim3(8, 8, NB), 256, 0, stream>>>(
      wib, 512, 0, xn, 512, 512 * 1024, qk, 1024, 1024 * 1024, 512,
      b_in, nullptr, 0, 0.f);
  // V proj: M=512 (c), N=1024 (token), K=512 -> vcm[b][c][token]
  gemm_bt<1><<<dim3(8, 4, NB), 256, 0, stream>>>(
      wib + 1024 * 512, 512, 0, xn, 512, 512 * 1024, vcm, 1024, 512 * 1024, 512,
      b_in + 1024, nullptr, 0, 0.f);

  // fused attention: scores + softmax + PV
  flash_kernel<<<256, 512, 0, stream>>>(qk, vcm, ao);

  // out proj: M=512 (c), N=1024 (i), K=512 -> out[b][c][i] + bias + residual
  gemm_bt<3><<<dim3(8, 4, NB), 256, 0, stream>>>(
      wob, 512, 0, ao, 512, 524288, out, 1024, 524288, 512,
      b_out, x, 524288, 0.f);
}

// Round 7
// 154.366 us; speedup vs baseline: 1.4914x; 1.0637x over previous
//
#include <hip/hip_runtime.h>
#include <hip/hip_bf16.h>
#include <cstdint>
#include <cstddef>

#define HW   1024   // H*W tokens
#define NC   512    // channels
#define NB   16     // batch
#define EPSV 1e-5f

typedef __hip_bfloat16 bf16;
typedef __attribute__((ext_vector_type(8))) __bf16 bf16x8;
typedef __attribute__((ext_vector_type(4))) float f32x4;

__device__ __forceinline__ float b2f(bf16 h) { return __bfloat162float(h); }

__device__ __forceinline__ void gload16(const void* g, void* l) {
  __builtin_amdgcn_global_load_lds(
      (const __attribute__((address_space(1))) uint32_t*)g,
      (__attribute__((address_space(3))) uint32_t*)l, 16, 0, 0);
}

// ---------------- weight fp32 -> bf16 convert ----------------
__global__ __launch_bounds__(256) void cvt_w_kernel(
    const float* __restrict__ wi, const float* __restrict__ wo,
    bf16* __restrict__ wib, bf16* __restrict__ wob) {
  int i = blockIdx.x * 256 + threadIdx.x;
  const float4* src;
  bf16* dst;
  int j;
  if (i < 196608) { src = (const float4*)wi; j = i; dst = wib; }
  else            { src = (const float4*)wo; j = i - 196608; dst = wob; }
  float4 v = src[j];
  union { bf16 h[4]; uint2 u; } p;
  p.h[0] = __float2bfloat16(v.x); p.h[1] = __float2bfloat16(v.y);
  p.h[2] = __float2bfloat16(v.z); p.h[3] = __float2bfloat16(v.w);
  *(uint2*)&dst[(size_t)j * 4] = p.u;
}

// ---------------- GroupNorm -> xn token-major bf16 [b][hw][c] ----------------
__global__ __launch_bounds__(256) void gn_kernel(
    const float* __restrict__ x, const float* __restrict__ gamma,
    const float* __restrict__ beta, bf16* __restrict__ xn) {
  int blk = blockIdx.x;
  int b = blk >> 5, g = blk & 31;
  size_t base = ((size_t)(b * NC + g * 16)) * HW;
  const float4* src4 = (const float4*)(x + base);
  int t = threadIdx.x;
  float s = 0.f, ss = 0.f;
  float4 v[16];
#pragma unroll
  for (int i = 0; i < 16; ++i) {
    v[i] = src4[t + i * 256];
    s  += v[i].x + v[i].y + v[i].z + v[i].w;
    ss += v[i].x * v[i].x + v[i].y * v[i].y + v[i].z * v[i].z + v[i].w * v[i].w;
  }
  __shared__ float red[256];
  red[t] = s; __syncthreads();
  for (int o = 128; o > 0; o >>= 1) { if (t < o) red[t] += red[t + o]; __syncthreads(); }
  float mean = red[0] * (1.f / 16384.f);
  __syncthreads();
  red[t] = ss; __syncthreads();
  for (int o = 128; o > 0; o >>= 1) { if (t < o) red[t] += red[t + o]; __syncthreads(); }
  float var = red[0] * (1.f / 16384.f) - mean * mean;
  float rstd = rsqrtf(var + EPSV);

  __shared__ bf16 sm[16][1032];
#pragma unroll
  for (int i = 0; i < 16; ++i) {
    int idx = t + i * 256;
    int c = idx >> 8;
    int hw4 = (idx & 255) * 4;
    float gm = gamma[g * 16 + c], bt = beta[g * 16 + c];
    union { bf16 h[4]; uint2 u; } p;
    p.h[0] = __float2bfloat16((v[i].x - mean) * rstd * gm + bt);
    p.h[1] = __float2bfloat16((v[i].y - mean) * rstd * gm + bt);
    p.h[2] = __float2bfloat16((v[i].z - mean) * rstd * gm + bt);
    p.h[3] = __float2bfloat16((v[i].w - mean) * rstd * gm + bt);
    *(uint2*)&sm[c][hw4] = p.u;
  }
  __syncthreads();
  bf16* dst = xn + (size_t)b * HW * NC + g * 16;
#pragma unroll
  for (int it = 0; it < 8; ++it) {
    int u = it * 256 + t;
    int hw = u >> 1;
    int c8 = (u & 1) * 8;
    union { bf16 h[8]; uint4 q; } p;
#pragma unroll
    for (int j = 0; j < 8; ++j) p.h[j] = sm[c8 + j][hw];
    *(uint4*)&dst[(size_t)hw * NC + c8] = p.q;
  }
}

// ---------------- universal MFMA GEMM: C[M][N] = A[M][K] * B^T[N][K] --------
// MODE 0: bf16 store transposed  C[col*ldc+row], bias[row]        (qk proj)
// MODE 1: bf16 store row-major   C[row*ldc+col], optional bias    (v proj)
// MODE 3: f32  store row-major, + bias[row] + resid               (out proj)
template <int MODE>
__global__ __launch_bounds__(256) void gemm_bt(
    const bf16* __restrict__ A, int lda, long long sA,
    const bf16* __restrict__ B, int ldb, long long sB,
    void* __restrict__ Cv, int ldc, long long sC,
    int K,
    const float* __restrict__ bias,
    const float* __restrict__ resid, long long sR,
    float scale) {
  __shared__ bf16 sT[2][128][32];
  int z = blockIdx.z;
  const bf16* Ab = A + (size_t)z * sA;
  const bf16* Bb = B + (size_t)z * sB;
  int n0 = blockIdx.x * 128, m0 = blockIdx.y * 128;
  int t = threadIdx.x;
  int l = t & 63, w = t >> 6;
  int wm = w >> 1, wn = w & 1;

  int srow = t >> 2;
  int scol = (t & 3) * 8;

  f32x4 acc[4][4] = {};

  const bf16* ga0 = Ab + (size_t)(m0 + srow) * lda + scol;
  const bf16* gb0 = Bb + (size_t)(n0 + srow) * ldb + scol;

  for (int k0 = 0; k0 < K; k0 += 32) {
    gload16(ga0 + k0, &sT[0][srow][scol]);
    gload16(ga0 + (size_t)64 * lda + k0, &sT[0][64 + srow][scol]);
    gload16(gb0 + k0, &sT[1][srow][scol]);
    gload16(gb0 + (size_t)64 * ldb + k0, &sT[1][64 + srow][scol]);
    __syncthreads();
    bf16x8 af[4], bfr[4];
    int kc = (l >> 4) * 8;
    int ra = wm * 64 + (l & 15);
    int rb = wn * 64 + (l & 15);
#pragma unroll
    for (int i = 0; i < 4; ++i) {
      af[i]  = *(const bf16x8*)&sT[0][ra + i * 16][kc];
      bfr[i] = *(const bf16x8*)&sT[1][rb + i * 16][kc];
    }
#pragma unroll
    for (int i = 0; i < 4; ++i)
#pragma unroll
      for (int j = 0; j < 4; ++j)
        acc[i][j] = __builtin_amdgcn_mfma_f32_16x16x32_bf16(af[i], bfr[j], acc[i][j], 0, 0, 0);
    __syncthreads();
  }

  int rbase = (l >> 4) * 4;
#pragma unroll
  for (int i = 0; i < 4; ++i) {
    int row = m0 + wm * 64 + i * 16 + rbase;
    float4 bv = make_float4(0.f, 0.f, 0.f, 0.f);
    if (MODE == 0 || MODE == 3) bv = *(const float4*)&bias[row];
    else if (MODE == 1) { if (bias) bv = *(const float4*)&bias[row]; }
#pragma unroll
    for (int j = 0; j < 4; ++j) {
      int col = n0 + wn * 64 + j * 16 + (l & 15);
      if (MODE == 0) {
        bf16* C = (bf16*)Cv + (size_t)z * sC;
        union { bf16 h[4]; uint2 u; } p;
        p.h[0] = __float2bfloat16(acc[i][j][0] + bv.x);
        p.h[1] = __float2bfloat16(acc[i][j][1] + bv.y);
        p.h[2] = __float2bfloat16(acc[i][j][2] + bv.z);
        p.h[3] = __float2bfloat16(acc[i][j][3] + bv.w);
        *(uint2*)&C[(size_t)col * ldc + row] = p.u;
      } else if (MODE == 1) {
        bf16* C = (bf16*)Cv + (size_t)z * sC;
        float bb[4] = {bv.x, bv.y, bv.z, bv.w};
#pragma unroll
        for (int r = 0; r < 4; ++r)
          C[(size_t)(row + r) * ldc + col] = __float2bfloat16(acc[i][j][r] + bb[r]);
      } else {
        float* C = (float*)Cv + (size_t)z * sC;
        float bb[4] = {bv.x, bv.y, bv.z, bv.w};
#pragma unroll
        for (int r = 0; r < 4; ++r) {
          size_t off = (size_t)(row + r) * ldc + col;
          C[off] = acc[i][j][r] + bb[r] + resid[(size_t)z * sR + off];
        }
      }
    }
  }
}

// ---------------- fused flash attention (LDS-staged K/V, phase-pipelined) ----
// grid: 256 wg, 512 threads (8 waves). KVBLK=64, 16 KV tiles.
// LDS 160KB: Qs [64i][512c] 64KB | K chunk dbuf 2x16KB ([64j][128c]) | Vs
// [512c][64j] 64KB. All staging via coalesced global_load_lds with
// pre-swizzled source; fragments via swizzled ds_read_b128 (<=2-way).
// QK role: wave=(jg 0..3, ih 0..1): S^T[16j][32i]. PV role: wave=64ch x 64i.
// P overlays the free K buffer (parity tile&1). No-max softmax (|s|<~8).
__global__ __launch_bounds__(512, 1) void flash_kernel(
    const bf16* __restrict__ qk, const bf16* __restrict__ vcm,
    bf16* __restrict__ ao) {
  __shared__ char lds[163840];
  char* Qs  = lds;              // 64KB
  char* Kb0 = lds + 65536;      // 16KB
  char* Kb1 = lds + 81920;      // 16KB
  char* Vs  = lds + 98304;      // 64KB

  int id = blockIdx.x;
  int xcd = id & 7, rest = id >> 3;
  int q = rest & 15, bh = rest >> 4;
  int b = xcd + bh * 8;         // batch -> fixed XCD (K/V L2 locality)
  int i0 = q * 64;

  const char* qkC = (const char*)qk + (size_t)b * 2097152;  // [1024 tok][1024 ch]
  const char* vC  = (const char*)vcm + (size_t)b * 1048576; // [512 ch][1024 tok]
  bf16* aob = ao + (size_t)b * (HW * NC) + (size_t)i0 * NC;

  int t = threadIdx.x, l = t & 63, w = t >> 6;
  int l15 = l & 15, lq = l >> 4;
  int jg = w >> 1, ih = w & 1;  // QK wave role
  int chb = w * 64;             // PV wave role

  // stage one 16KB K chunk [64 j][128 c] (rows 256B), swizzle ((row&7)<<4)
  auto stage_k = [&](int tile_, int c_, char* dst_) {
#pragma unroll
    for (int qq = 0; qq < 2; ++qq) {
      int drow = w * 8 + qq * 4 + lq;          // 0..63
      int cb = l15 * 16;                        // 0..240
      gload16(qkC + (size_t)(tile_ * 64 + drow) * 2048 + 1024 + c_ * 256
                  + (cb ^ ((drow & 7) << 4)),
              dst_ + w * 2048 + qq * 1024 + l * 16);
    }
  };
  // stage 8KB of Vs [512 c][64 j] (rows 128B), part v_=0..7
  auto stage_v = [&](int tile_, int v_) {
    int ch = v_ * 64 + w * 8 + (l >> 3);
    int cb = (l & 7) * 16;
    gload16(vC + (size_t)ch * 2048 + tile_ * 128 + (cb ^ ((ch & 7) << 4)),
            Vs + v_ * 8192 + w * 1024 + l * 16);
  };

  // ---- prologue: stage Q (swizzled) + K chunk 0 of tile 0
  {
    const char* qbase = qkC + (size_t)i0 * 2048;
#pragma unroll
    for (int it = 0; it < 8; ++it) {
      int s = it * 8192 + t * 16;
      int i = s >> 10, wb = s & 1023;
      gload16(qbase + (size_t)i * 2048 + (wb ^ ((i & 7) << 4)), Qs + s);
    }
  }
  stage_k(0, 0, Kb0);

  float lacc[2] = {0.f, 0.f};
  f32x4 o[4][4] = {};                       // [mi: ch frag][ni: i frag]
  const float scl = 0.044194173824159216f;  // 1/sqrt(512)

  __syncthreads();   // prologue drain (vmcnt via barrier semantics)

  for (int tile = 0; tile < 16; ++tile) {
    char* PsBuf = (tile & 1) ? Kb1 : Kb0;
    f32x4 s[2] = {};
    // ---- 4 K-chunk phases: stage(next) || mfma(cur) ; barrier
#pragma unroll
    for (int p = 0; p < 4; ++p) {
      if (p < 3) {
        char* kd = ((p + 1 + tile) & 1) ? Kb1 : Kb0;
        stage_k(tile, p + 1, kd);
      }
      stage_v(tile, p * 2);
      stage_v(tile, p * 2 + 1);
      const char* kcur = ((p + tile) & 1) ? Kb1 : Kb0;
      int krow = jg * 16 + l15;
#pragma unroll
      for (int k2 = 0; k2 < 4; ++k2) {
        bf16x8 kf = *(const bf16x8*)(kcur + krow * 256
                      + ((k2 * 64 + lq * 16) ^ ((krow & 7) << 4)));
#pragma unroll
        for (int ni = 0; ni < 2; ++ni) {
          int i = ih * 32 + ni * 16 + l15;
          bf16x8 qf = *(const bf16x8*)(Qs + i * 1024
                        + ((p * 256 + k2 * 64 + lq * 16) ^ ((i & 7) << 4)));
          s[ni] = __builtin_amdgcn_mfma_f32_16x16x32_bf16(kf, qf, s[ni], 0, 0, 0);
        }
      }
      __syncthreads();
    }
    // ---- softmax (no max-subtraction) + pack P into free K buffer
#pragma unroll
    for (int ni = 0; ni < 2; ++ni) {
      int i = ih * 32 + ni * 16 + l15;
      float p0 = __expf(s[ni][0] * scl);
      float p1 = __expf(s[ni][1] * scl);
      float p2 = __expf(s[ni][2] * scl);
      float p3 = __expf(s[ni][3] * scl);
      lacc[ni] += p0 + p1 + p2 + p3;
      union { bf16 h[4]; uint64_t u; } pk;
      pk.h[0] = __float2bfloat16(p0); pk.h[1] = __float2bfloat16(p1);
      pk.h[2] = __float2bfloat16(p2); pk.h[3] = __float2bfloat16(p3);
      *(uint64_t*)(PsBuf + i * 128 + ((jg * 32 + lq * 8) ^ ((i & 7) << 4))) = pk.u;
    }
    __syncthreads();  // Ps ready; Vs fully staged (drained at phase barriers)
    // ---- PV phase (+ prefetch next tile's K chunk 0 into the other buffer)
    if (tile < 15) {
      char* kd = ((tile + 1) & 1) ? Kb1 : Kb0;
      stage_k(tile + 1, 0, kd);
    }
#pragma unroll
    for (int ks = 0; ks < 2; ++ks) {
      bf16x8 vf[4];
#pragma unroll
      for (int mi = 0; mi < 4; ++mi) {
        int ch = chb + mi * 16 + l15;
        vf[mi] = *(const bf16x8*)(Vs + ch * 128
                   + ((ks * 64 + lq * 16) ^ ((ch & 7) << 4)));
      }
#pragma unroll
      for (int ni = 0; ni < 4; ++ni) {
        int i = ni * 16 + l15;
        bf16x8 pf = *(const bf16x8*)(PsBuf + i * 128
                      + ((ks * 64 + lq * 16) ^ ((i & 7) << 4)));
#pragma unroll
        for (int mi = 0; mi < 4; ++mi)
          o[mi][ni] = __builtin_amdgcn_mfma_f32_16x16x32_bf16(vf[mi], pf, o[mi][ni], 0, 0, 0);
      }
    }
    __syncthreads();  // PV done -> next tile may overwrite PsBuf & Vs
  }

  // ---- epilogue: row-sum combine (redl overlays dead Qs) + store
  float* redl = (float*)Qs;  // [4 jg][64 i]
#pragma unroll
  for (int ni = 0; ni < 2; ++ni) {
    float v = lacc[ni];
    v += __shfl_xor(v, 16);
    v += __shfl_xor(v, 32);
    if (l < 16) redl[jg * 64 + ih * 32 + ni * 16 + l] = v;
  }
  __syncthreads();
  float linv[4];
#pragma unroll
  for (int ni = 0; ni < 4; ++ni) {
    int i = ni * 16 + l15;
    linv[ni] = 1.f / (redl[i] + redl[64 + i] + redl[128 + i] + redl[192 + i]);
  }
#pragma unroll
  for (int mi = 0; mi < 4; ++mi)
#pragma unroll
    for (int ni = 0; ni < 4; ++ni) {
      union { bf16 h[4]; uint64_t u; } pk;
#pragma unroll
      for (int r = 0; r < 4; ++r)
        pk.h[r] = __float2bfloat16(o[mi][ni][r] * linv[ni]);
      int i = ni * 16 + l15;
      int ch = chb + mi * 16 + lq * 4;
      *(uint64_t*)(aob + (size_t)i * NC + ch) = pk.u;
    }
}

extern "C" void kernel_launch(void* const* d_in, const int* in_sizes, int n_in,
                              void* d_out, int out_size, void* d_ws, size_t ws_size,
                              hipStream_t stream) {
  const float* x     = (const float*)d_in[0];
  const float* gamma = (const float*)d_in[1];
  const float* beta  = (const float*)d_in[2];
  const float* w_in  = (const float*)d_in[3];
  const float* b_in  = (const float*)d_in[4];
  const float* w_out = (const float*)d_in[5];
  const float* b_out = (const float*)d_in[6];
  float* out = (float*)d_out;

  char* w = (char*)d_ws;
  bf16* xn  = (bf16*)w;                              // 16 MB, token-major [b][hw][c]
  bf16* ao  = xn;                                    // reuse after projections
  bf16* qk  = (bf16*)(w + ((size_t)16 << 20));       // 32 MB, [b][token][1024] (q|k)
  bf16* vcm = (bf16*)(w + ((size_t)48 << 20));       // 16 MB, [b][c][token]
  bf16* wib = (bf16*)(w + ((size_t)64 << 20));       // 1.5 MB
  bf16* wob = (bf16*)(w + ((size_t)64 << 20) + ((size_t)3 << 19));  // 0.5 MB

  cvt_w_kernel<<<1024, 256, 0, stream>>>(w_in, w_out, wib, wob);
  gn_kernel<<<NB * 32, 256, 0, stream>>>(x, gamma, beta, xn);

  // QK proj: M=1024 (o: q|k), N=1024 (token), K=512 -> qk[b][token][o]
  gemm_bt<0><<<dim3(8, 8, NB), 256, 0, stream>>>(
      wib, 512, 0, xn, 512, 512 * 1024, qk, 1024, 1024 * 1024, 512,
      b_in, nullptr, 0, 0.f);
  // V proj: M=512 (c), N=1024 (token), K=512 -> vcm[b][c][token]
  gemm_bt<1><<<dim3(8, 4, NB), 256, 0, stream>>>(
      wib + 1024 * 512, 512, 0, xn, 512, 512 * 1024, vcm, 1024, 512 * 1024, 512,
      b_in + 1024, nullptr, 0, 0.f);

  // fused attention: scores + softmax + PV
  flash_kernel<<<256, 512, 0, stream>>>(qk, vcm, ao);

  // out proj: M=512 (c), N=1024 (i), K=512 -> out[b][c][i] + bias + residual
  gemm_bt<3><<<dim3(8, 4, NB), 256, 0, stream>>>(
      wob, 512, 0, ao, 512, 524288, out, 1024, 524288, 512,
      b_out, x, 524288, 0.f);
}

// Round 8
// 146.688 us; speedup vs baseline: 1.5695x; 1.0523x over previous
//
#include <hip/hip_runtime.h>
#include <hip/hip_bf16.h>
#include <cstdint>
#include <cstddef>

#define HW   1024   // H*W tokens
#define NC   512    // channels
#define NB   16     // batch
#define EPSV 1e-5f

typedef __hip_bfloat16 bf16;
typedef __attribute__((ext_vector_type(8))) __bf16 bf16x8;
typedef __attribute__((ext_vector_type(4))) float f32x4;

__device__ __forceinline__ float b2f(bf16 h) { return __bfloat162float(h); }

__device__ __forceinline__ void gload16(const void* g, void* l) {
  __builtin_amdgcn_global_load_lds(
      (const __attribute__((address_space(1))) uint32_t*)g,
      (__attribute__((address_space(3))) uint32_t*)l, 16, 0, 0);
}

// ---------------- weight fp32 -> bf16 convert ----------------
__global__ __launch_bounds__(256) void cvt_w_kernel(
    const float* __restrict__ wi, const float* __restrict__ wo,
    bf16* __restrict__ wib, bf16* __restrict__ wob) {
  int i = blockIdx.x * 256 + threadIdx.x;
  const float4* src;
  bf16* dst;
  int j;
  if (i < 196608) { src = (const float4*)wi; j = i; dst = wib; }
  else            { src = (const float4*)wo; j = i - 196608; dst = wob; }
  float4 v = src[j];
  union { bf16 h[4]; uint2 u; } p;
  p.h[0] = __float2bfloat16(v.x); p.h[1] = __float2bfloat16(v.y);
  p.h[2] = __float2bfloat16(v.z); p.h[3] = __float2bfloat16(v.w);
  *(uint2*)&dst[(size_t)j * 4] = p.u;
}

// ---------------- GroupNorm -> xn token-major bf16 [b][hw][c] ----------------
__global__ __launch_bounds__(256) void gn_kernel(
    const float* __restrict__ x, const float* __restrict__ gamma,
    const float* __restrict__ beta, bf16* __restrict__ xn) {
  int blk = blockIdx.x;
  int b = blk >> 5, g = blk & 31;
  size_t base = ((size_t)(b * NC + g * 16)) * HW;
  const float4* src4 = (const float4*)(x + base);
  int t = threadIdx.x;
  float s = 0.f, ss = 0.f;
  float4 v[16];
#pragma unroll
  for (int i = 0; i < 16; ++i) {
    v[i] = src4[t + i * 256];
    s  += v[i].x + v[i].y + v[i].z + v[i].w;
    ss += v[i].x * v[i].x + v[i].y * v[i].y + v[i].z * v[i].z + v[i].w * v[i].w;
  }
  __shared__ float red[256];
  red[t] = s; __syncthreads();
  for (int o = 128; o > 0; o >>= 1) { if (t < o) red[t] += red[t + o]; __syncthreads(); }
  float mean = red[0] * (1.f / 16384.f);
  __syncthreads();
  red[t] = ss; __syncthreads();
  for (int o = 128; o > 0; o >>= 1) { if (t < o) red[t] += red[t + o]; __syncthreads(); }
  float var = red[0] * (1.f / 16384.f) - mean * mean;
  float rstd = rsqrtf(var + EPSV);

  __shared__ bf16 sm[16][1032];
#pragma unroll
  for (int i = 0; i < 16; ++i) {
    int idx = t + i * 256;
    int c = idx >> 8;
    int hw4 = (idx & 255) * 4;
    float gm = gamma[g * 16 + c], bt = beta[g * 16 + c];
    union { bf16 h[4]; uint2 u; } p;
    p.h[0] = __float2bfloat16((v[i].x - mean) * rstd * gm + bt);
    p.h[1] = __float2bfloat16((v[i].y - mean) * rstd * gm + bt);
    p.h[2] = __float2bfloat16((v[i].z - mean) * rstd * gm + bt);
    p.h[3] = __float2bfloat16((v[i].w - mean) * rstd * gm + bt);
    *(uint2*)&sm[c][hw4] = p.u;
  }
  __syncthreads();
  bf16* dst = xn + (size_t)b * HW * NC + g * 16;
#pragma unroll
  for (int it = 0; it < 8; ++it) {
    int u = it * 256 + t;
    int hw = u >> 1;
    int c8 = (u & 1) * 8;
    union { bf16 h[8]; uint4 q; } p;
#pragma unroll
    for (int j = 0; j < 8; ++j) p.h[j] = sm[c8 + j][hw];
    *(uint4*)&dst[(size_t)hw * NC + c8] = p.q;
  }
}

// ---------------- universal MFMA GEMM: C[M][N] = A[M][K] * B^T[N][K] --------
// MODE 0: bf16 store transposed  C[col*ldc+row], bias[row]        (qk proj)
// MODE 1: bf16 store row-major   C[row*ldc+col], optional bias    (v proj)
template <int MODE>
__global__ __launch_bounds__(256) void gemm_bt(
    const bf16* __restrict__ A, int lda, long long sA,
    const bf16* __restrict__ B, int ldb, long long sB,
    void* __restrict__ Cv, int ldc, long long sC,
    int K,
    const float* __restrict__ bias) {
  __shared__ bf16 sT[2][128][32];
  int z = blockIdx.z;
  const bf16* Ab = A + (size_t)z * sA;
  const bf16* Bb = B + (size_t)z * sB;
  int n0 = blockIdx.x * 128, m0 = blockIdx.y * 128;
  int t = threadIdx.x;
  int l = t & 63, w = t >> 6;
  int wm = w >> 1, wn = w & 1;

  int srow = t >> 2;
  int scol = (t & 3) * 8;

  f32x4 acc[4][4] = {};

  const bf16* ga0 = Ab + (size_t)(m0 + srow) * lda + scol;
  const bf16* gb0 = Bb + (size_t)(n0 + srow) * ldb + scol;

  for (int k0 = 0; k0 < K; k0 += 32) {
    gload16(ga0 + k0, &sT[0][srow][scol]);
    gload16(ga0 + (size_t)64 * lda + k0, &sT[0][64 + srow][scol]);
    gload16(gb0 + k0, &sT[1][srow][scol]);
    gload16(gb0 + (size_t)64 * ldb + k0, &sT[1][64 + srow][scol]);
    __syncthreads();
    bf16x8 af[4], bfr[4];
    int kc = (l >> 4) * 8;
    int ra = wm * 64 + (l & 15);
    int rb = wn * 64 + (l & 15);
#pragma unroll
    for (int i = 0; i < 4; ++i) {
      af[i]  = *(const bf16x8*)&sT[0][ra + i * 16][kc];
      bfr[i] = *(const bf16x8*)&sT[1][rb + i * 16][kc];
    }
#pragma unroll
    for (int i = 0; i < 4; ++i)
#pragma unroll
      for (int j = 0; j < 4; ++j)
        acc[i][j] = __builtin_amdgcn_mfma_f32_16x16x32_bf16(af[i], bfr[j], acc[i][j], 0, 0, 0);
    __syncthreads();
  }

  int rbase = (l >> 4) * 4;
#pragma unroll
  for (int i = 0; i < 4; ++i) {
    int row = m0 + wm * 64 + i * 16 + rbase;
    float4 bv = make_float4(0.f, 0.f, 0.f, 0.f);
    if (MODE == 0) bv = *(const float4*)&bias[row];
    else if (MODE == 1) { if (bias) bv = *(const float4*)&bias[row]; }
#pragma unroll
    for (int j = 0; j < 4; ++j) {
      int col = n0 + wn * 64 + j * 16 + (l & 15);
      if (MODE == 0) {
        bf16* C = (bf16*)Cv + (size_t)z * sC;
        union { bf16 h[4]; uint2 u; } p;
        p.h[0] = __float2bfloat16(acc[i][j][0] + bv.x);
        p.h[1] = __float2bfloat16(acc[i][j][1] + bv.y);
        p.h[2] = __float2bfloat16(acc[i][j][2] + bv.z);
        p.h[3] = __float2bfloat16(acc[i][j][3] + bv.w);
        *(uint2*)&C[(size_t)col * ldc + row] = p.u;
      } else {
        bf16* C = (bf16*)Cv + (size_t)z * sC;
        float bb[4] = {bv.x, bv.y, bv.z, bv.w};
#pragma unroll
        for (int r = 0; r < 4; ++r)
          C[(size_t)(row + r) * ldc + col] = __float2bfloat16(acc[i][j][r] + bb[r]);
      }
    }
  }
}

// ---------------- fused flash attention + out-projection ----------------
// grid: 256 wg, 512 threads (8 waves). KVBLK=64, 16 KV tiles (as round 7).
// After the KV loop: normalized O -> swizzled ao_lds tile [64 i][512 c]
// (overlays dead Q buffer), then 512x64x512 GEMM vs w_out staged from L2 in
// 32KB double-buffered chunks; epilogue adds bias + fp32 residual, stores out.
__global__ __launch_bounds__(512, 1) void flash_kernel(
    const bf16* __restrict__ qk, const bf16* __restrict__ vcm,
    const bf16* __restrict__ wout, const float* __restrict__ b_out,
    const float* __restrict__ x, float* __restrict__ out) {
  __shared__ char lds[163840];
  char* Qs  = lds;              // 64KB (Q during KV loop; ao tile after)
  char* Kb0 = lds + 65536;      // 16KB
  char* Kb1 = lds + 81920;      // 16KB
  char* Vs  = lds + 98304;      // 64KB
  char* Wb0 = lds + 65536;      // 32KB (Kb0+Kb1, reused for W chunks)
  char* Wb1 = lds + 98304;      // 32KB (first half of Vs)
  float* redl = (float*)(lds + 131072);  // 1KB (second half of Vs)

  int id = blockIdx.x;
  int xcd = id & 7, rest = id >> 3;
  int q = rest & 15, bh = rest >> 4;
  int b = xcd + bh * 8;         // batch -> fixed XCD (K/V L2 locality)
  int i0 = q * 64;

  const char* qkC = (const char*)qk + (size_t)b * 2097152;  // [1024 tok][1024 ch]
  const char* vC  = (const char*)vcm + (size_t)b * 1048576; // [512 ch][1024 tok]
  const char* wC  = (const char*)wout;                      // [512 co][512 c]

  int t = threadIdx.x, l = t & 63, w = t >> 6;
  int l15 = l & 15, lq = l >> 4;
  int jg = w >> 1, ih = w & 1;  // QK wave role
  int chb = w * 64;             // PV / out-GEMM wave role

  auto stage_k = [&](int tile_, int c_, char* dst_) {
#pragma unroll
    for (int qq = 0; qq < 2; ++qq) {
      int drow = w * 8 + qq * 4 + lq;
      int cb = l15 * 16;
      gload16(qkC + (size_t)(tile_ * 64 + drow) * 2048 + 1024 + c_ * 256
                  + (cb ^ ((drow & 7) << 4)),
              dst_ + w * 2048 + qq * 1024 + l * 16);
    }
  };
  auto stage_v = [&](int tile_, int v_) {
    int ch = v_ * 64 + w * 8 + (l >> 3);
    int cb = (l & 7) * 16;
    gload16(vC + (size_t)ch * 2048 + tile_ * 128 + (cb ^ ((ch & 7) << 4)),
            Vs + v_ * 8192 + w * 1024 + l * 16);
  };
  auto stage_w = [&](int kc_, char* dst_) {
#pragma unroll
    for (int it = 0; it < 4; ++it) {
      int idx = it * 512 + t;
      int row = idx >> 2, cb = (idx & 3) * 16;
      gload16(wC + (size_t)row * 1024 + kc_ * 64 + (cb ^ ((row & 3) << 4)),
              dst_ + idx * 16);
    }
  };

  // ---- prologue: stage Q (swizzled) + K chunk 0 of tile 0
  {
    const char* qbase = qkC + (size_t)i0 * 2048;
#pragma unroll
    for (int it = 0; it < 8; ++it) {
      int s = it * 8192 + t * 16;
      int i = s >> 10, wb = s & 1023;
      gload16(qbase + (size_t)i * 2048 + (wb ^ ((i & 7) << 4)), Qs + s);
    }
  }
  stage_k(0, 0, Kb0);

  float lacc[2] = {0.f, 0.f};
  f32x4 o[4][4] = {};                       // [mi: ch frag][ni: i frag]
  const float scl = 0.044194173824159216f;  // 1/sqrt(512)

  __syncthreads();   // prologue drain

  for (int tile = 0; tile < 16; ++tile) {
    char* PsBuf = (tile & 1) ? Kb1 : Kb0;
    f32x4 s[2] = {};
#pragma unroll
    for (int p = 0; p < 4; ++p) {
      if (p < 3) {
        char* kd = ((p + 1 + tile) & 1) ? Kb1 : Kb0;
        stage_k(tile, p + 1, kd);
      }
      stage_v(tile, p * 2);
      stage_v(tile, p * 2 + 1);
      const char* kcur = ((p + tile) & 1) ? Kb1 : Kb0;
      int krow = jg * 16 + l15;
#pragma unroll
      for (int k2 = 0; k2 < 4; ++k2) {
        bf16x8 kf = *(const bf16x8*)(kcur + krow * 256
                      + ((k2 * 64 + lq * 16) ^ ((krow & 7) << 4)));
#pragma unroll
        for (int ni = 0; ni < 2; ++ni) {
          int i = ih * 32 + ni * 16 + l15;
          bf16x8 qf = *(const bf16x8*)(Qs + i * 1024
                        + ((p * 256 + k2 * 64 + lq * 16) ^ ((i & 7) << 4)));
          s[ni] = __builtin_amdgcn_mfma_f32_16x16x32_bf16(kf, qf, s[ni], 0, 0, 0);
        }
      }
      __syncthreads();
    }
#pragma unroll
    for (int ni = 0; ni < 2; ++ni) {
      int i = ih * 32 + ni * 16 + l15;
      float p0 = __expf(s[ni][0] * scl);
      float p1 = __expf(s[ni][1] * scl);
      float p2 = __expf(s[ni][2] * scl);
      float p3 = __expf(s[ni][3] * scl);
      lacc[ni] += p0 + p1 + p2 + p3;
      union { bf16 h[4]; uint64_t u; } pk;
      pk.h[0] = __float2bfloat16(p0); pk.h[1] = __float2bfloat16(p1);
      pk.h[2] = __float2bfloat16(p2); pk.h[3] = __float2bfloat16(p3);
      *(uint64_t*)(PsBuf + i * 128 + ((jg * 32 + lq * 8) ^ ((i & 7) << 4))) = pk.u;
    }
    __syncthreads();  // Ps ready; Vs fully staged
    if (tile < 15) {
      char* kd = ((tile + 1) & 1) ? Kb1 : Kb0;
      stage_k(tile + 1, 0, kd);
    }
#pragma unroll
    for (int ks = 0; ks < 2; ++ks) {
      bf16x8 vf[4];
#pragma unroll
      for (int mi = 0; mi < 4; ++mi) {
        int ch = chb + mi * 16 + l15;
        vf[mi] = *(const bf16x8*)(Vs + ch * 128
                   + ((ks * 64 + lq * 16) ^ ((ch & 7) << 4)));
      }
#pragma unroll
      for (int ni = 0; ni < 4; ++ni) {
        int i = ni * 16 + l15;
        bf16x8 pf = *(const bf16x8*)(PsBuf + i * 128
                      + ((ks * 64 + lq * 16) ^ ((i & 7) << 4)));
#pragma unroll
        for (int mi = 0; mi < 4; ++mi)
          o[mi][ni] = __builtin_amdgcn_mfma_f32_16x16x32_bf16(vf[mi], pf, o[mi][ni], 0, 0, 0);
      }
    }
    __syncthreads();  // PV done -> next tile may overwrite PsBuf & Vs
  }

  // ---- fused out-projection ----
  // issue W chunk 0 while doing the row-sum combine (K/V buffers are dead)
  stage_w(0, Wb0);
#pragma unroll
  for (int ni = 0; ni < 2; ++ni) {
    float v = lacc[ni];
    v += __shfl_xor(v, 16);
    v += __shfl_xor(v, 32);
    if (l < 16) redl[jg * 64 + ih * 32 + ni * 16 + l] = v;
  }
  __syncthreads();  // redl ready; W chunk 0 drained
  float linv[4];
#pragma unroll
  for (int ni = 0; ni < 4; ++ni) {
    int i = ni * 16 + l15;
    linv[ni] = 1.f / (redl[i] + redl[64 + i] + redl[128 + i] + redl[192 + i]);
  }
  // normalized O -> ao_lds [64 i][512 c] bf16, swizzled (overlays dead Qs)
#pragma unroll
  for (int mi = 0; mi < 4; ++mi)
#pragma unroll
    for (int ni = 0; ni < 4; ++ni) {
      union { bf16 h[4]; uint64_t u; } pk;
#pragma unroll
      for (int r = 0; r < 4; ++r)
        pk.h[r] = __float2bfloat16(o[mi][ni][r] * linv[ni]);
      int i = ni * 16 + l15;
      int c2 = (chb + mi * 16 + lq * 4) * 2;   // byte offset of c (8B aligned)
      *(uint64_t*)(Qs + i * 1024 + (c2 ^ ((i & 7) << 4))) = pk.u;
    }
  __syncthreads();  // ao_lds ready

  // GEMM: out[co][i] = sum_c W[co][c] * ao[i][c], K=512 in 16 steps of 32
  f32x4 acc2[4][4] = {};
#pragma unroll
  for (int kc = 0; kc < 16; ++kc) {
    if (kc < 15) stage_w(kc + 1, ((kc + 1) & 1) ? Wb1 : Wb0);
    const char* Wc = (kc & 1) ? Wb1 : Wb0;
    bf16x8 wf[4];
#pragma unroll
    for (int mi = 0; mi < 4; ++mi) {
      int row = chb + mi * 16 + l15;
      wf[mi] = *(const bf16x8*)(Wc + row * 64 + ((lq * 16) ^ ((row & 3) << 4)));
    }
#pragma unroll
    for (int ni = 0; ni < 4; ++ni) {
      int i = ni * 16 + l15;
      bf16x8 pf = *(const bf16x8*)(Qs + i * 1024
                    + ((kc * 64 + lq * 16) ^ ((i & 7) << 4)));
#pragma unroll
      for (int mi = 0; mi < 4; ++mi)
        acc2[mi][ni] = __builtin_amdgcn_mfma_f32_16x16x32_bf16(wf[mi], pf, acc2[mi][ni], 0, 0, 0);
    }
    __syncthreads();  // W chunk kc+1 drained; all waves done with cur buffer
  }

  // epilogue: + bias + residual, store fp32 out[b][co][i0+i]
  const float* xb = x + (size_t)b * 524288;
  float* ob = out + (size_t)b * 524288;
#pragma unroll
  for (int mi = 0; mi < 4; ++mi) {
    int cbase = chb + mi * 16 + lq * 4;
    float4 bv = *(const float4*)&b_out[cbase];
    float bb[4] = {bv.x, bv.y, bv.z, bv.w};
#pragma unroll
    for (int ni = 0; ni < 4; ++ni) {
      int i = i0 + ni * 16 + l15;
#pragma unroll
      for (int r = 0; r < 4; ++r) {
        size_t off = (size_t)(cbase + r) * 1024 + i;
        ob[off] = acc2[mi][ni][r] + bb[r] + xb[off];
      }
    }
  }
}

extern "C" void kernel_launch(void* const* d_in, const int* in_sizes, int n_in,
                              void* d_out, int out_size, void* d_ws, size_t ws_size,
                              hipStream_t stream) {
  const float* x     = (const float*)d_in[0];
  const float* gamma = (const float*)d_in[1];
  const float* beta  = (const float*)d_in[2];
  const float* w_in  = (const float*)d_in[3];
  const float* b_in  = (const float*)d_in[4];
  const float* w_out = (const float*)d_in[5];
  const float* b_out = (const float*)d_in[6];
  float* out = (float*)d_out;

  char* w = (char*)d_ws;
  bf16* xn  = (bf16*)w;                              // 16 MB, token-major [b][hw][c]
  bf16* qk  = (bf16*)(w + ((size_t)16 << 20));       // 32 MB, [b][token][1024] (q|k)
  bf16* vcm = (bf16*)(w + ((size_t)48 << 20));       // 16 MB, [b][c][token]
  bf16* wib = (bf16*)(w + ((size_t)64 << 20));       // 1.5 MB
  bf16* wob = (bf16*)(w + ((size_t)64 << 20) + ((size_t)3 << 19));  // 0.5 MB

  cvt_w_kernel<<<1024, 256, 0, stream>>>(w_in, w_out, wib, wob);
  gn_kernel<<<NB * 32, 256, 0, stream>>>(x, gamma, beta, xn);

  // QK proj: M=1024 (o: q|k), N=1024 (token), K=512 -> qk[b][token][o]
  gemm_bt<0><<<dim3(8, 8, NB), 256, 0, stream>>>(
      wib, 512, 0, xn, 512, 512 * 1024, qk, 1024, 1024 * 1024, 512, b_in);
  // V proj: M=512 (c), N=1024 (token), K=512 -> vcm[b][c][token]
  gemm_bt<1><<<dim3(8, 4, NB), 256, 0, stream>>>(
      wib + 1024 * 512, 512, 0, xn, 512, 512 * 1024, vcm, 1024, 512 * 1024, 512,
      b_in + 1024);

  // fused attention: scores + softmax + PV + out-projection + residual
  flash_kernel<<<256, 512, 0, stream>>>(qk, vcm, wob, b_out, x, out);
}